// Round 9
// baseline (391.949 us; speedup 1.0000x reference)
//
#include <hip/hip_runtime.h>

// ---------------- problem constants ----------------
constexpr int NPEP = 20000, NMHC = 5000, NTCR = 100000;
constexpr int EPM = 200000, EMT = 400000, BB = 50000;
constexpr int MAXU = 50000;

typedef __attribute__((ext_vector_type(8))) short bf16x8;
typedef __attribute__((ext_vector_type(4))) float f32x4;

__device__ inline ushort f2bf(float x) {
    union { float f; unsigned u; } v; v.f = x;
    unsigned r = (v.u + 0x7FFF + ((v.u >> 16) & 1)) >> 16;
    return (ushort)r;
}
__device__ inline float bf2f(ushort b) {
    union { unsigned u; float f; } t; t.u = ((unsigned)b) << 16; return t.f;
}
__device__ inline void bf2x2(unsigned u, float& a, float& b) {
    union { unsigned x; float f; } t1, t2;
    t1.x = u << 16; t2.x = u & 0xffff0000u;
    a = t1.f; b = t2.f;
}
__device__ inline ushort4 f4bf(float4 v) {
    return make_ushort4(f2bf(v.x), f2bf(v.y), f2bf(v.z), f2bf(v.w));
}

constexpr int RS  = 40;    // mfma LDS row stride
constexpr int RS1 = 136;   // tcr etc tile stride (K=128)
constexpr int RS2 = 264;   // tcr 256-col tile stride

// ---------------- device: dual-output fused GEMM tile (mhc layers) ----------------
template <int K, int NB0>
__device__ void fused_tile(ushort* Als, ushort* Wls, int tid, int bx, int by, int M,
                           const ushort* __restrict__ A, const ushort* __restrict__ W,
                           const float* __restrict__ bias,
                           ushort* __restrict__ out0, int s0, ushort* __restrict__ out1) {
    const int m0 = bx * 128, n0 = by * 128;
    const int lane = tid & 63, w = tid >> 6;
    const int wm = w >> 1, wn = w & 1;
    const int m16 = lane & 15, q = lane >> 4;

    f32x4 acc[4][4] = {};

    for (int k0 = 0; k0 < K; k0 += 32) {
        bf16x8 a_st[2], w_st[2];
#pragma unroll
        for (int r = 0; r < 2; r++) {
            int chunk = tid + r * 256;
            int row = chunk >> 2, off = (chunk & 3) * 8;
            int ga = min(m0 + row, M - 1);
            a_st[r] = *(const bf16x8*)(A + (size_t)ga * K + k0 + off);
            w_st[r] = *(const bf16x8*)(W + (size_t)(n0 + row) * K + k0 + off);
        }
        __syncthreads();
#pragma unroll
        for (int r = 0; r < 2; r++) {
            int chunk = tid + r * 256;
            int row = chunk >> 2, off = (chunk & 3) * 8;
            *(bf16x8*)(&Als[row * RS + off]) = a_st[r];
            *(bf16x8*)(&Wls[row * RS + off]) = w_st[r];
        }
        __syncthreads();
        bf16x8 af[4], bf[4];
#pragma unroll
        for (int t = 0; t < 4; t++) {
            af[t] = *(const bf16x8*)(&Als[(wm * 64 + t * 16 + m16) * RS + q * 8]);
            bf[t] = *(const bf16x8*)(&Wls[(wn * 64 + t * 16 + m16) * RS + q * 8]);
        }
#pragma unroll
        for (int mt = 0; mt < 4; mt++)
#pragma unroll
            for (int nt = 0; nt < 4; nt++)
                acc[mt][nt] = __builtin_amdgcn_mfma_f32_16x16x32_bf16(af[mt], bf[nt], acc[mt][nt], 0, 0, 0);
    }

    const bool g1 = (by >= NB0);
#pragma unroll
    for (int mt = 0; mt < 4; mt++) {
#pragma unroll
        for (int i = 0; i < 4; i++) {
            int row = m0 + wm * 64 + mt * 16 + q * 4 + i;
            if (row >= M) continue;
#pragma unroll
            for (int nt = 0; nt < 4; nt++) {
                int col = n0 + wn * 64 + nt * 16 + m16;
                float v = acc[mt][nt][i];
                if (!g1) {
                    v += bias[col];
                    v = fmaxf(v, 0.f);
                    out0[(size_t)row * s0 + col] = f2bf(v);
                } else {
                    out1[(size_t)row * 256 + (col - NB0 * 128)] = f2bf(v);
                }
            }
        }
    }
}

// ---------------- device: bf16-out GEMM tile (Hp / Hm) ----------------
template <int K, bool HASB, bool AF32>
__device__ void out_tile(ushort* Als, ushort* Wls, int tid, int bx, int by, int M,
                         const void* __restrict__ Av, const ushort* __restrict__ W,
                         const float* __restrict__ bias, ushort* __restrict__ out) {
    const int m0 = bx * 128, n0 = by * 128;
    const int lane = tid & 63, w = tid >> 6;
    const int wm = w >> 1, wn = w & 1;
    const int m16 = lane & 15, q = lane >> 4;

    f32x4 acc[4][4] = {};

    for (int k0 = 0; k0 < K; k0 += 32) {
        bf16x8 a_st[2], w_st[2];
#pragma unroll
        for (int r = 0; r < 2; r++) {
            int chunk = tid + r * 256;
            int row = chunk >> 2, off = (chunk & 3) * 8;
            int ga = min(m0 + row, M - 1);
            if constexpr (AF32) {
                const float* Af = (const float*)Av;
                float4 f0 = *(const float4*)(Af + (size_t)ga * K + k0 + off);
                float4 f1 = *(const float4*)(Af + (size_t)ga * K + k0 + off + 4);
                ushort4 u0 = f4bf(f0), u1 = f4bf(f1);
                bf16x8 av;
                av[0] = (short)u0.x; av[1] = (short)u0.y; av[2] = (short)u0.z; av[3] = (short)u0.w;
                av[4] = (short)u1.x; av[5] = (short)u1.y; av[6] = (short)u1.z; av[7] = (short)u1.w;
                a_st[r] = av;
            } else {
                a_st[r] = *(const bf16x8*)((const ushort*)Av + (size_t)ga * K + k0 + off);
            }
            w_st[r] = *(const bf16x8*)(W + (size_t)(n0 + row) * K + k0 + off);
        }
        __syncthreads();
#pragma unroll
        for (int r = 0; r < 2; r++) {
            int chunk = tid + r * 256;
            int row = chunk >> 2, off = (chunk & 3) * 8;
            *(bf16x8*)(&Als[row * RS + off]) = a_st[r];
            *(bf16x8*)(&Wls[row * RS + off]) = w_st[r];
        }
        __syncthreads();
        bf16x8 af[4], bf[4];
#pragma unroll
        for (int t = 0; t < 4; t++) {
            af[t] = *(const bf16x8*)(&Als[(wm * 64 + t * 16 + m16) * RS + q * 8]);
            bf[t] = *(const bf16x8*)(&Wls[(wn * 64 + t * 16 + m16) * RS + q * 8]);
        }
#pragma unroll
        for (int mt = 0; mt < 4; mt++)
#pragma unroll
            for (int nt = 0; nt < 4; nt++)
                acc[mt][nt] = __builtin_amdgcn_mfma_f32_16x16x32_bf16(af[mt], bf[nt], acc[mt][nt], 0, 0, 0);
    }

#pragma unroll
    for (int mt = 0; mt < 4; mt++) {
#pragma unroll
        for (int i = 0; i < 4; i++) {
            int row = m0 + wm * 64 + mt * 16 + q * 4 + i;
            if (row >= M) continue;
#pragma unroll
            for (int nt = 0; nt < 4; nt++) {
                int col = n0 + wn * 64 + nt * 16 + m16;
                float v = acc[mt][nt][i];
                if (HASB) v += bias[col];
                out[(size_t)row * 256 + col] = f2bf(v);
            }
        }
    }
}

// ---------------- device: single-Z neighbor-mean gather pass (32 rows -> A LDS) ----------------
__device__ void gather_pass(ushort* A, const int* __restrict__ list,
                            const int* __restrict__ rp, const int* __restrict__ csr_src,
                            const ushort* __restrict__ Z, int m0, int M, int tid) {
    const int g = tid >> 5, gl = tid & 31;
    for (int rr = g; rr < 32; rr += 8) {
        int cr = min(m0 + rr, M - 1);
        int orig = list[cr];
        int e0 = rp[orig], e1 = rp[orig + 1];
        int deg = e1 - e0;
        float s[8] = {};
        for (int eb = e0; eb < e1; eb += 32) {
            int dc = min(32, e1 - eb);
            int sidx_l = (gl < dc) ? csr_src[eb + gl] : 0;
            for (int e = 0; e < dc; e++) {
                int sidx = __shfl(sidx_l, e, 32);
                uint4 u = *(const uint4*)(Z + (size_t)sidx * 256 + gl * 8);
                float x, y;
                bf2x2(u.x, x, y); s[0] += x; s[1] += y;
                bf2x2(u.y, x, y); s[2] += x; s[3] += y;
                bf2x2(u.z, x, y); s[4] += x; s[5] += y;
                bf2x2(u.w, x, y); s[6] += x; s[7] += y;
            }
        }
        float es = 1.f / fmaxf((float)deg, 1.f);
        uint4 w;
        w.x = (unsigned)f2bf(s[0] * es) | ((unsigned)f2bf(s[1] * es) << 16);
        w.y = (unsigned)f2bf(s[2] * es) | ((unsigned)f2bf(s[3] * es) << 16);
        w.z = (unsigned)f2bf(s[4] * es) | ((unsigned)f2bf(s[5] * es) << 16);
        w.w = (unsigned)f2bf(s[6] * es) | ((unsigned)f2bf(s[7] * es) << 16);
        *(uint4*)(&A[rr * RS2 + gl * 8]) = w;
    }
}

// ---------------- merged prep + histogram kernel ----------------
// deg/cur/mark zeroed beforehand via hipMemsetAsync. Blocks 0..2539 = histogram,
// the rest = weight packing / Acat1 / wcomp.
__global__ __launch_bounds__(256) void preph_kernel(
    const int* __restrict__ dst_pm, const int* __restrict__ dst_mt,
    const int* __restrict__ pack_tcr,
    int* __restrict__ deg_pm, int* __restrict__ deg_mt, int* __restrict__ mark,
    const float4* __restrict__ Wr1f, ushort4* __restrict__ Wr1_b,
    const float4* __restrict__ Wr2f, ushort4* __restrict__ Wr2_b,
    const float* __restrict__ head_W1, ushort4* __restrict__ W1b_b, ushort4* __restrict__ W1c_b,
    const float* __restrict__ l1_pm_Wl, const float* __restrict__ l1_pm_Wr,
    const float* __restrict__ l1_mt_Wl, ushort* __restrict__ Wcat1_b,
    const float* __restrict__ l2_pm_Wl, const float* __restrict__ l2_pm_Wr,
    const float* __restrict__ l2_mt_Wl, ushort* __restrict__ Wcat2_b,
    const float4* __restrict__ emb_mhc, ushort* __restrict__ Acat1,
    const float* __restrict__ proj_W, const float* __restrict__ proj_b,
    ushort* __restrict__ Wcomp_b, float* __restrict__ bp) {
    __shared__ float red[128];
    const int b = blockIdx.x, tid = threadIdx.x;
    if (b < 2540) {
        int t = b * 256 + tid;
        if (t < EPM) atomicAdd(&deg_pm[dst_pm[t]], 1);
        else if (t < EPM + EMT) atomicAdd(&deg_mt[dst_mt[t - EPM]], 1);
        else if (t < EPM + EMT + BB) mark[pack_tcr[t - EPM - EMT]] = 1;  // benign race
    } else if (b < 2572) {
        int i = (b - 2540) * 256 + tid;
        if (i < 8192) Wr1_b[i] = f4bf(Wr1f[i]);
    } else if (b < 2636) {
        int i = (b - 2572) * 256 + tid;
        if (i < 16384) Wr2_b[i] = f4bf(Wr2f[i]);
    } else if (b < 2700) {
        int i = (b - 2636) * 256 + tid;
        if (i < 16384) {
            int n = i >> 6, k4 = (i & 63) * 4;
            W1b_b[i] = f4bf(*(const float4*)(head_W1 + (size_t)n * 768 + 256 + k4));
        }
    } else if (b < 2764) {
        int i = (b - 2700) * 256 + tid;
        if (i < 16384) {
            int n = i >> 6, k4 = (i & 63) * 4;
            W1c_b[i] = f4bf(*(const float4*)(head_W1 + (size_t)n * 768 + 512 + k4));
        }
    } else if (b < 3276) {
        int idx = (b - 2764) * 256 + tid;   // 512x256
        if (idx < 131072) {
            int r = idx >> 8, k = idx & 255;
            float v;
            if (r < 256) v = (k < 128) ? l1_pm_Wl[r * 128 + k] : l1_pm_Wr[r * 128 + (k - 128)];
            else         v = (k < 128) ? 0.f : l1_mt_Wl[(r - 256) * 128 + (k - 128)];
            Wcat1_b[idx] = f2bf(v);
        }
    } else if (b < 4044) {
        int idx = (b - 3276) * 256 + tid;   // 512x384
        if (idx < 196608) {
            int r = idx / 384, k = idx - r * 384;
            float v;
            if (r < 256) v = (k < 128) ? l2_pm_Wl[r * 128 + k] : l2_pm_Wr[r * 256 + (k - 128)];
            else         v = (k < 128) ? 0.f : l2_mt_Wl[(r - 256) * 256 + (k - 128)];
            Wcat2_b[idx] = f2bf(v);
        }
    } else if (b < 4669) {
        int i4 = (b - 4044) * 256 + tid;
        if (i4 < 160000) {
            int r = i4 >> 5, c4 = (i4 & 31) * 4;
            *(ushort4*)(Acat1 + (size_t)r * 256 + 128 + c4) = f4bf(emb_mhc[i4]);
        }
    } else {
        // wcomp: one block per output row i (0..255)
        int i = b - 4669;
        const float* w1row = head_W1 + (size_t)i * 768;
        if (tid < 128) {
            float acc = 0.f;
            for (int k = 0; k < 256; k++) acc += w1row[k] * proj_W[k * 128 + tid];
            Wcomp_b[i * 128 + tid] = f2bf(acc);
            red[tid] = w1row[2 * tid] * proj_b[2 * tid] + w1row[2 * tid + 1] * proj_b[2 * tid + 1];
        }
        __syncthreads();
        if (tid < 64) { red[tid] += red[tid + 64]; }
        __syncthreads();
        if (tid < 32) { red[tid] += red[tid + 32]; }
        __syncthreads();
        if (tid == 0) {
            float s = 0.f;
            for (int j = 0; j < 32; j++) s += red[j];
            bp[i] = s;
        }
    }
}

// ---------------- merged blocksum (raw partials) ----------------
__global__ __launch_bounds__(256) void blocksum2_kernel(const int* __restrict__ deg_pm,
                                                        const int* __restrict__ deg_mt,
                                                        const int* __restrict__ mark,
                                                        int* __restrict__ bsum_pm,
                                                        int* __restrict__ bsum_mt,
                                                        int* __restrict__ bsum_mk) {
    __shared__ int red[256];
    const int tid = threadIdx.x;
    const int* deg; int n, bi; int* bsum;
    if (blockIdx.x < 5) { deg = deg_pm; n = NMHC; bi = blockIdx.x; bsum = bsum_pm; }
    else if (blockIdx.x < 103) { deg = deg_mt; n = NTCR; bi = blockIdx.x - 5; bsum = bsum_mt; }
    else { deg = mark; n = NTCR; bi = blockIdx.x - 103; bsum = bsum_mk; }
    const int base = bi * 1024;
    int s = 0;
#pragma unroll
    for (int j = 0; j < 4; j++) {
        int i = base + tid + j * 256;
        if (i < n) s += deg[i];
    }
    red[tid] = s;
    __syncthreads();
    for (int off = 128; off > 0; off >>= 1) {
        if (tid < off) red[tid] += red[tid + off];
        __syncthreads();
    }
    if (tid == 0) bsum[bi] = red[0];
}

// ---------------- emit: rowptrs + compact list + inv map (inline exclusive base) ----------------
__global__ __launch_bounds__(256) void emit2_kernel(const int* __restrict__ deg_pm,
                                                    const int* __restrict__ deg_mt,
                                                    const int* __restrict__ mark,
                                                    const int* __restrict__ bsum_pm,
                                                    const int* __restrict__ bsum_mt,
                                                    const int* __restrict__ bsum_mk,
                                                    int* __restrict__ rp_pm,
                                                    int* __restrict__ rp_mt,
                                                    int* __restrict__ list,
                                                    int* __restrict__ inv,
                                                    int* __restrict__ nrows) {
    __shared__ int tsum[256];
    const int tid = threadIdx.x;
    const int* deg; const int* bsum; int* rp; int n, nb, bi, mode;
    if (blockIdx.x < 5) { deg = deg_pm; bsum = bsum_pm; rp = rp_pm; n = NMHC; nb = 5; bi = blockIdx.x; mode = 0; }
    else if (blockIdx.x < 103) { deg = deg_mt; bsum = bsum_mt; rp = rp_mt; n = NTCR; nb = 98; bi = blockIdx.x - 5; mode = 0; }
    else { deg = mark; bsum = bsum_mk; rp = nullptr; n = NTCR; nb = 98; bi = blockIdx.x - 103; mode = 1; }
    // exclusive base = sum of raw partials j < bi
    tsum[tid] = (tid < bi) ? bsum[tid] : 0;
    __syncthreads();
    for (int off = 128; off > 0; off >>= 1) {
        if (tid < off) tsum[tid] += tsum[tid + off];
        __syncthreads();
    }
    const int base = tsum[0];
    __syncthreads();
    const int i0 = bi * 1024 + tid * 4;
    int4 v = make_int4(0, 0, 0, 0);
    if (i0 + 3 < n) v = *(const int4*)(deg + i0);
    else if (i0 < n) {
        int t[4] = {0, 0, 0, 0};
        for (int j = 0; j < 4 && i0 + j < n; j++) t[j] = deg[i0 + j];
        v = make_int4(t[0], t[1], t[2], t[3]);
    }
    tsum[tid] = v.x + v.y + v.z + v.w;
    __syncthreads();
    for (int off = 1; off < 256; off <<= 1) {
        int t = (tid >= off) ? tsum[tid - off] : 0;
        __syncthreads();
        tsum[tid] += t;
        __syncthreads();
    }
    int ex = ((tid > 0) ? tsum[tid - 1] : 0) + base;
    if (mode == 0) {
        if (i0 + 3 < n) {
            int r1 = ex + v.x, r2 = r1 + v.y, r3 = r2 + v.z;
            *(int4*)(rp + i0) = make_int4(ex, r1, r2, r3);
        } else if (i0 < n) {
            int r = ex;
            int vv[4] = {v.x, v.y, v.z, v.w};
            for (int j = 0; j < 4 && i0 + j < n; j++) { rp[i0 + j] = r; r += vv[j]; }
        }
        if (bi == nb - 1 && tid == 255) rp[n] = base + tsum[255];
    } else {
        int p = ex;
        int vv[4] = {v.x, v.y, v.z, v.w};
#pragma unroll
        for (int j = 0; j < 4; j++) {
            if (i0 + j < n && vv[j]) { list[p] = i0 + j; inv[i0 + j] = p; p++; }
        }
        if (bi == nb - 1 && tid == 255) nrows[0] = base + tsum[255];
    }
}

// ---------------- merged CSR fill ----------------
__global__ void fill2_kernel(const int* __restrict__ src_pm, const int* __restrict__ dst_pm,
                             const int* __restrict__ src_mt, const int* __restrict__ dst_mt,
                             const int* __restrict__ rp_pm, int* __restrict__ cur_pm, int* __restrict__ csr_pm,
                             const int* __restrict__ rp_mt, int* __restrict__ cur_mt, int* __restrict__ csr_mt) {
    int t = blockIdx.x * blockDim.x + threadIdx.x;
    if (t < EPM) {
        int d = dst_pm[t];
        int pos = atomicAdd(&cur_pm[d], 1);
        csr_pm[rp_pm[d] + pos] = src_pm[t];
    } else if (t < EPM + EMT) {
        int t2 = t - EPM;
        int d = dst_mt[t2];
        int pos = atomicAdd(&cur_mt[d], 1);
        csr_mt[rp_mt[d] + pos] = src_mt[t2];
    }
}

// ---------------- merged: pm gather (shfl-parallel) + pt remap ----------------
__global__ __launch_bounds__(256) void gph_kernel(
    const int* __restrict__ rp, const int* __restrict__ csr_src,
    const float* __restrict__ X, ushort* __restrict__ A1, ushort* __restrict__ A2,
    const int* __restrict__ pack_tcr, const int* __restrict__ inv, int* __restrict__ pt_c) {
    const int tid = threadIdx.x;
    const int b = blockIdx.x;
    if (b < 625) {
        const int r = b * 8 + (tid >> 5);
        const int lane = tid & 31;
        if (r >= NMHC) return;
        const int e0 = rp[r], e1 = rp[r + 1];
        float4 s = make_float4(0.f, 0.f, 0.f, 0.f);
        for (int eb = e0; eb < e1; eb += 32) {
            int dc = min(32, e1 - eb);
            int sidx_l = (lane < dc) ? csr_src[eb + lane] : 0;
            for (int e = 0; e < dc; e++) {
                int sidx = __shfl(sidx_l, e, 32);
                float4 v = ((const float4*)(X + (long)sidx * 128))[lane];
                s.x += v.x; s.y += v.y; s.z += v.z; s.w += v.w;
            }
        }
        float sc = 1.f / fmaxf((float)(e1 - e0), 1.f);
        ushort4 o = make_ushort4(f2bf(s.x * sc), f2bf(s.y * sc), f2bf(s.z * sc), f2bf(s.w * sc));
        *(ushort4*)(A1 + (size_t)r * 256 + lane * 4) = o;
        *(ushort4*)(A2 + (size_t)r * 384 + lane * 4) = o;
    } else {
        int i = (b - 625) * 256 + tid;
        if (i < BB) pt_c[i] = inv[pack_tcr[i]];
    }
}

// ---------------- mhc fused GEMM launch + Hp tiles ----------------
template <int K>
__global__ __launch_bounds__(256, 2) void fusedhp_kernel(
    int M, const ushort* __restrict__ A, const ushort* __restrict__ W,
    const float* __restrict__ bias,
    ushort* __restrict__ out0, int s0, ushort* __restrict__ out1,
    int hpBy, const float* __restrict__ emb_pep, const ushort* __restrict__ Wcomp,
    const float* __restrict__ bp, ushort* __restrict__ Hp) {
    __shared__ ushort Als[128 * RS];
    __shared__ ushort Wls[128 * RS];
    const int tid = threadIdx.x;
    const int b = blockIdx.x;
    if (b < 160)
        fused_tile<K, 2>(Als, Wls, tid, b % 40, b / 40, M, A, W, bias, out0, s0, out1);
    else
        out_tile<128, true, true>(Als, Wls, tid, b - 160, hpBy, NPEP, emb_pep, Wcomp, bp, Hp);
}

// ---------------- fused TCR chain (2-buffer LDS, 4 blocks/CU) + Hm GEMM ----------------
__global__ __launch_bounds__(256, 4) void tcrhm_kernel(
    const int* __restrict__ nrowsp, const int* __restrict__ list,
    const int* __restrict__ rp, const int* __restrict__ csr_src,
    const ushort* __restrict__ Z1, const ushort* __restrict__ Z2,
    const float* __restrict__ emb_tcr,
    const ushort* __restrict__ Wr1, const ushort* __restrict__ Wr2,
    const ushort* __restrict__ W1c,
    const float* __restrict__ bl1, const float* __restrict__ bl2,
    ushort* __restrict__ Ht_c,
    const ushort* __restrict__ mhc2, const ushort* __restrict__ W1b,
    ushort* __restrict__ Hm) {
    union SM {
        struct { ushort B[32 * RS2]; ushort A[32 * RS2]; } t;                       // 33792 B
        struct { ushort Als[128 * RS]; ushort Wls[128 * RS]; } g;                   // 20480 B
    };
    __shared__ SM sm;
    const int tid = threadIdx.x;

    if (blockIdx.x >= 1563) {
        int v = blockIdx.x - 1563;             // 0..79
        out_tile<256, false, false>(sm.g.Als, sm.g.Wls, tid, v % 40, v / 40, NMHC,
                                    mhc2, W1b, nullptr, Hm);
        return;
    }

    const int M = nrowsp[0];
    const int m0 = blockIdx.x * 32;
    if (m0 >= M) return;
    const int lane = tid & 63, w = tid >> 6;   // wave w: cols w*64..w*64+63
    const int m16 = lane & 15, q = lane >> 4;

    // ---- stage 0: emb_tcr rows f32->bf16 -> B (RS1) ----
#pragma unroll
    for (int r = 0; r < 4; r++) {
        int chunk = tid + r * 256;             // 1024 chunks: 32 rows x 32 float4
        int row = chunk >> 5, c4 = (chunk & 31) * 4;
        int grow = list[min(m0 + row, M - 1)];
        float4 v = *(const float4*)(emb_tcr + (size_t)grow * 128 + c4);
        *(ushort4*)(&sm.t.B[row * RS1 + c4]) = f4bf(v);
    }

    // ---- gather pass 1: Z1 neighbor-mean -> A ----
    gather_pass(sm.t.A, list, rp, csr_src, Z1, m0, M, tid);
    __syncthreads();

    // ---- stage 1a: T1 = relu(etc @ Wr1^T + bl1 + A) ----
    {
        f32x4 acc[2][4] = {};
        for (int k0 = 0; k0 < 128; k0 += 32) {
            bf16x8 af[2], bf[4];
#pragma unroll
            for (int t = 0; t < 2; t++)
                af[t] = *(const bf16x8*)(&sm.t.B[(t * 16 + m16) * RS1 + k0 + q * 8]);
#pragma unroll
            for (int t = 0; t < 4; t++)
                bf[t] = *(const bf16x8*)(Wr1 + (size_t)(w * 64 + t * 16 + m16) * 128 + k0 + q * 8);
#pragma unroll
            for (int mt = 0; mt < 2; mt++)
#pragma unroll
                for (int nt = 0; nt < 4; nt++)
                    acc[mt][nt] = __builtin_amdgcn_mfma_f32_16x16x32_bf16(af[mt], bf[nt], acc[mt][nt], 0, 0, 0);
        }
        __syncthreads();                       // B reads done before rewrite
#pragma unroll
        for (int mt = 0; mt < 2; mt++)
#pragma unroll
            for (int i = 0; i < 4; i++) {
                int lr = mt * 16 + q * 4 + i;
#pragma unroll
                for (int nt = 0; nt < 4; nt++) {
                    int col = w * 64 + nt * 16 + m16;
                    float v = acc[mt][nt][i] + bl1[col] + bf2f(sm.t.A[lr * RS2 + col]);
                    sm.t.B[lr * RS2 + col] = f2bf(fmaxf(v, 0.f));
                }
            }
    }
    __syncthreads();                           // A (Z1-mean) fully consumed

    // ---- gather pass 2: Z2 neighbor-mean -> A (buffer reuse) ----
    gather_pass(sm.t.A, list, rp, csr_src, Z2, m0, M, tid);
    __syncthreads();

    // ---- stage 1b: T = relu(T1 @ Wr2^T + bl2 + A) ----
    {
        f32x4 acc[2][4] = {};
        for (int k0 = 0; k0 < 256; k0 += 32) {
            bf16x8 af[2], bf[4];
#pragma unroll
            for (int t = 0; t < 2; t++)
                af[t] = *(const bf16x8*)(&sm.t.B[(t * 16 + m16) * RS2 + k0 + q * 8]);
#pragma unroll
            for (int t = 0; t < 4; t++)
                bf[t] = *(const bf16x8*)(Wr2 + (size_t)(w * 64 + t * 16 + m16) * 256 + k0 + q * 8);
#pragma unroll
            for (int mt = 0; mt < 2; mt++)
#pragma unroll
                for (int nt = 0; nt < 4; nt++)
                    acc[mt][nt] = __builtin_amdgcn_mfma_f32_16x16x32_bf16(af[mt], bf[nt], acc[mt][nt], 0, 0, 0);
        }
        __syncthreads();
#pragma unroll
        for (int mt = 0; mt < 2; mt++)
#pragma unroll
            for (int i = 0; i < 4; i++) {
                int lr = mt * 16 + q * 4 + i;
#pragma unroll
                for (int nt = 0; nt < 4; nt++) {
                    int col = w * 64 + nt * 16 + m16;
                    float v = acc[mt][nt][i] + bl2[col] + bf2f(sm.t.A[lr * RS2 + col]);
                    sm.t.B[lr * RS2 + col] = f2bf(fmaxf(v, 0.f));
                }
            }
    }
    __syncthreads();

    // ---- stage 2: Ht_tile = T @ W1c^T -> B ----
    {
        f32x4 acc[2][4] = {};
        for (int k0 = 0; k0 < 256; k0 += 32) {
            bf16x8 af[2], bf[4];
#pragma unroll
            for (int t = 0; t < 2; t++)
                af[t] = *(const bf16x8*)(&sm.t.B[(t * 16 + m16) * RS2 + k0 + q * 8]);
#pragma unroll
            for (int t = 0; t < 4; t++)
                bf[t] = *(const bf16x8*)(W1c + (size_t)(w * 64 + t * 16 + m16) * 256 + k0 + q * 8);
#pragma unroll
            for (int mt = 0; mt < 2; mt++)
#pragma unroll
                for (int nt = 0; nt < 4; nt++)
                    acc[mt][nt] = __builtin_amdgcn_mfma_f32_16x16x32_bf16(af[mt], bf[nt], acc[mt][nt], 0, 0, 0);
        }
        __syncthreads();
#pragma unroll
        for (int mt = 0; mt < 2; mt++)
#pragma unroll
            for (int i = 0; i < 4; i++) {
                int lr = mt * 16 + q * 4 + i;
#pragma unroll
                for (int nt = 0; nt < 4; nt++) {
                    int col = w * 64 + nt * 16 + m16;
                    sm.t.B[lr * RS2 + col] = f2bf(acc[mt][nt][i]);
                }
            }
    }
    __syncthreads();

    // coalesced COMPACT writeback
#pragma unroll
    for (int r = 0; r < 4; r++) {
        int chunk = tid + r * 256;
        int row = chunk >> 5, c8 = (chunk & 31) * 8;
        if (m0 + row < M)
            *(uint4*)(Ht_c + (size_t)(m0 + row) * 256 + c8) = *(const uint4*)(&sm.t.B[row * RS2 + c8]);
    }
}

// ---------------- combine ----------------
__global__ __launch_bounds__(256) void combine_kernel(
    const ushort* __restrict__ Hp, const ushort* __restrict__ Hm, const ushort* __restrict__ Ht,
    const int* __restrict__ pp, const int* __restrict__ pm, const int* __restrict__ pt_c,
    const float* __restrict__ b1, const float* __restrict__ W2, const float* __restrict__ b2,
    float* __restrict__ out) {
    const int tid = threadIdx.x;
    const int lane = tid & 63, w = tid >> 6;
    const int c = lane * 4;
    const float4 b1v = *(const float4*)(b1 + c);
    const float4 w2v = *(const float4*)(W2 + c);
    const float b2v = b2[0];
    const int base = blockIdx.x * 32 + w * 8;
#pragma unroll
    for (int t = 0; t < 8; t++) {
        int i = base + t;
        if (i >= BB) return;
        int ra = pp[i], rb = pm[i], rc = pt_c[i];
        ushort4 ua = *(const ushort4*)(Hp + (size_t)ra * 256 + c);
        ushort4 ub = *(const ushort4*)(Hm + (size_t)rb * 256 + c);
        ushort4 uc = *(const ushort4*)(Ht + (size_t)rc * 256 + c);
        float h0 = fmaxf(bf2f(ua.x) + bf2f(ub.x) + bf2f(uc.x) + b1v.x, 0.f);
        float h1 = fmaxf(bf2f(ua.y) + bf2f(ub.y) + bf2f(uc.y) + b1v.y, 0.f);
        float h2 = fmaxf(bf2f(ua.z) + bf2f(ub.z) + bf2f(uc.z) + b1v.z, 0.f);
        float h3 = fmaxf(bf2f(ua.w) + bf2f(ub.w) + bf2f(uc.w) + b1v.w, 0.f);
        float p = h0 * w2v.x + h1 * w2v.y + h2 * w2v.z + h3 * w2v.w;
#pragma unroll
        for (int off = 32; off > 0; off >>= 1) p += __shfl_down(p, off);
        if (lane == 0) out[i] = p + b2v;
    }
}

// ---------------- launch ----------------
extern "C" void kernel_launch(void* const* d_in, const int* in_sizes, int n_in,
                              void* d_out, int out_size, void* d_ws, size_t ws_size,
                              hipStream_t stream) {
    const float* emb_pep = (const float*)d_in[0];
    const float* emb_mhc = (const float*)d_in[1];
    const float* emb_tcr = (const float*)d_in[2];
    const int* src_pm = (const int*)d_in[3];
    const int* dst_pm = (const int*)d_in[4];
    const int* src_mt = (const int*)d_in[5];
    const int* dst_mt = (const int*)d_in[6];
    const int* pack_pep = (const int*)d_in[7];
    const int* pack_mhc = (const int*)d_in[8];
    const int* pack_tcr = (const int*)d_in[9];
    const float* l1_pm_Wl = (const float*)d_in[10];
    const float* l1_pm_bl = (const float*)d_in[11];
    const float* l1_pm_Wr = (const float*)d_in[12];
    const float* l1_mt_Wl = (const float*)d_in[13];
    const float* l1_mt_bl = (const float*)d_in[14];
    const float* l1_mt_Wr = (const float*)d_in[15];
    const float* l2_pm_Wl = (const float*)d_in[16];
    const float* l2_pm_bl = (const float*)d_in[17];
    const float* l2_pm_Wr = (const float*)d_in[18];
    const float* l2_mt_Wl = (const float*)d_in[19];
    const float* l2_mt_bl = (const float*)d_in[20];
    const float* l2_mt_Wr = (const float*)d_in[21];
    const float* proj_W = (const float*)d_in[22];
    const float* proj_b = (const float*)d_in[23];
    const float* head_W1 = (const float*)d_in[24];
    const float* head_b1 = (const float*)d_in[25];
    const float* head_W2 = (const float*)d_in[26];
    const float* head_b2 = (const float*)d_in[27];
    float* out = (float*)d_out;

    // ---------------- workspace layout ----------------
    int* ib = (int*)d_ws;
    int* deg_pm = ib;                 // 5000
    int* cur_pm = ib + 5000;          // 5000
    int* deg_mt = ib + 10000;         // 100000
    int* cur_mt = ib + 110000;        // 100000
    int* mark   = ib + 210000;        // 100000  [zero region: first 310000 ints, via memset]
    int* rp_pm  = ib + 310000;        // 5001 (pad 5008)
    int* rp_mt  = ib + 315008;        // 100001 (pad 100008)
    int* csr_pm = ib + 415016;        // 200000
    int* csr_mt = ib + 615016;        // 400000
    int* bsum_pm = ib + 1015016;      // 160
    int* bsum_mt = ib + 1015176;      // 160
    int* bsum_mk = ib + 1015336;      // 160
    int* nrows   = ib + 1015496;      // 8
    int* list    = ib + 1015504;      // 50048 -> 1065552
    int* inv     = ib + 1065552;      // 100000 -> 1165552
    int* pt_c    = ib + 1165552;      // 50048 -> 1215600

    float* f = (float*)(ib + 1215600);
    float* bp = f;                    // 256

    ushort* u = (ushort*)(f + 256);
    ushort* Wcat1_b = u;              // 131072
    ushort* Wcat2_b = u + 131072;     // 196608
    ushort* W1b_b   = u + 327680;     // 65536
    ushort* W1c_b   = u + 393216;     // 65536
    ushort* Wcomp_b = u + 458752;     // 32768
    ushort* Wr1_b   = u + 491520;     // 32768
    ushort* Wr2_b   = u + 524288;     // 65536
    ushort* Acat1   = u + 589824;     // 1280000
    ushort* Acat2   = u + 1869824;    // 1920000
    ushort* Zb1     = u + 3789824;    // 1280000
    ushort* Zb2     = u + 5069824;    // 1280000
    ushort* mhc2_b  = u + 6349824;    // 1280000
    ushort* Hp_b    = u + 7629824;    // 5120000
    ushort* Hm_b    = u + 12749824;   // 1280000
    ushort* Ht_c    = u + 14029824;   // 12800000 (50000x256 compact)

    // 0. zero deg/cur/mark (stream-ordered DMA)
    hipMemsetAsync(ib, 0, 310000 * sizeof(int), stream);

    // 1. merged prep + histogram
    preph_kernel<<<4925, 256, 0, stream>>>(
        dst_pm, dst_mt, pack_tcr, deg_pm, deg_mt, mark,
        (const float4*)l1_mt_Wr, (ushort4*)Wr1_b,
        (const float4*)l2_mt_Wr, (ushort4*)Wr2_b,
        head_W1, (ushort4*)W1b_b, (ushort4*)W1c_b,
        l1_pm_Wl, l1_pm_Wr, l1_mt_Wl, Wcat1_b,
        l2_pm_Wl, l2_pm_Wr, l2_mt_Wl, Wcat2_b,
        (const float4*)emb_mhc, Acat1,
        proj_W, proj_b, Wcomp_b, bp);

    // 2-4. CSR build + compaction
    blocksum2_kernel<<<201, 256, 0, stream>>>(deg_pm, deg_mt, mark, bsum_pm, bsum_mt, bsum_mk);
    emit2_kernel<<<201, 256, 0, stream>>>(deg_pm, deg_mt, mark, bsum_pm, bsum_mt, bsum_mk,
                                          rp_pm, rp_mt, list, inv, nrows);
    fill2_kernel<<<(EPM + EMT + 255) / 256, 256, 0, stream>>>(
        src_pm, dst_pm, src_mt, dst_mt, rp_pm, cur_pm, csr_pm, rp_mt, cur_mt, csr_mt);

    // 5. pm gather + pt remap
    gph_kernel<<<821, 256, 0, stream>>>(
        rp_pm, csr_pm, emb_pep, Acat1, Acat2, pack_tcr, inv, pt_c);

    // 6-7. mhc layers + Hp halves
    fusedhp_kernel<256><<<317, 256, 0, stream>>>(
        NMHC, Acat1, Wcat1_b, l1_pm_bl, Acat2 + 128, 384, Zb1,
        0, emb_pep, Wcomp_b, bp, Hp_b);
    fusedhp_kernel<384><<<317, 256, 0, stream>>>(
        NMHC, Acat2, Wcat2_b, l2_pm_bl, mhc2_b, 256, Zb2,
        1, emb_pep, Wcomp_b, bp, Hp_b);

    // 8. fused tcr chain (compact Ht) + Hm tiles
    tcrhm_kernel<<<1563 + 80, 256, 0, stream>>>(
        nrows, list, rp_mt, csr_mt, Zb1, Zb2, emb_tcr,
        Wr1_b, Wr2_b, W1c_b, l1_mt_bl, l2_mt_bl, Ht_c,
        mhc2_b, W1b_b, Hm_b);

    // 9. combine
    combine_kernel<<<(BB + 31) / 32, 256, 0, stream>>>(
        Hp_b, Hm_b, Ht_c, pack_pep, pack_mhc, pt_c,
        head_b1, head_W2, head_b2, out);
}

// Round 10
// 386.838 us; speedup vs baseline: 1.0132x; 1.0132x over previous
//
#include <hip/hip_runtime.h>

// ---------------- problem constants ----------------
constexpr int NPEP = 20000, NMHC = 5000, NTCR = 100000;
constexpr int EPM = 200000, EMT = 400000, BB = 50000;
constexpr int MAXU = 50000;

typedef __attribute__((ext_vector_type(8))) short bf16x8;
typedef __attribute__((ext_vector_type(4))) float f32x4;

__device__ inline ushort f2bf(float x) {
    union { float f; unsigned u; } v; v.f = x;
    unsigned r = (v.u + 0x7FFF + ((v.u >> 16) & 1)) >> 16;
    return (ushort)r;
}
__device__ inline float bf2f(ushort b) {
    union { unsigned u; float f; } t; t.u = ((unsigned)b) << 16; return t.f;
}
__device__ inline void bf2x2(unsigned u, float& a, float& b) {
    union { unsigned x; float f; } t1, t2;
    t1.x = u << 16; t2.x = u & 0xffff0000u;
    a = t1.f; b = t2.f;
}
__device__ inline ushort4 f4bf(float4 v) {
    return make_ushort4(f2bf(v.x), f2bf(v.y), f2bf(v.z), f2bf(v.w));
}

constexpr int RS  = 40;    // mfma LDS row stride
constexpr int RS1 = 136;   // tcr etc tile stride (K=128)
constexpr int RS2 = 264;   // tcr 256-col tile stride

// ---------------- device: dual-output fused GEMM tile (mhc layers) ----------------
template <int K, int NB0>
__device__ void fused_tile(ushort* Als, ushort* Wls, int tid, int bx, int by, int M,
                           const ushort* __restrict__ A, const ushort* __restrict__ W,
                           const float* __restrict__ bias,
                           ushort* __restrict__ out0, int s0, ushort* __restrict__ out1) {
    const int m0 = bx * 128, n0 = by * 128;
    const int lane = tid & 63, w = tid >> 6;
    const int wm = w >> 1, wn = w & 1;
    const int m16 = lane & 15, q = lane >> 4;

    f32x4 acc[4][4] = {};

    for (int k0 = 0; k0 < K; k0 += 32) {
        bf16x8 a_st[2], w_st[2];
#pragma unroll
        for (int r = 0; r < 2; r++) {
            int chunk = tid + r * 256;
            int row = chunk >> 2, off = (chunk & 3) * 8;
            int ga = min(m0 + row, M - 1);
            a_st[r] = *(const bf16x8*)(A + (size_t)ga * K + k0 + off);
            w_st[r] = *(const bf16x8*)(W + (size_t)(n0 + row) * K + k0 + off);
        }
        __syncthreads();
#pragma unroll
        for (int r = 0; r < 2; r++) {
            int chunk = tid + r * 256;
            int row = chunk >> 2, off = (chunk & 3) * 8;
            *(bf16x8*)(&Als[row * RS + off]) = a_st[r];
            *(bf16x8*)(&Wls[row * RS + off]) = w_st[r];
        }
        __syncthreads();
        bf16x8 af[4], bf[4];
#pragma unroll
        for (int t = 0; t < 4; t++) {
            af[t] = *(const bf16x8*)(&Als[(wm * 64 + t * 16 + m16) * RS + q * 8]);
            bf[t] = *(const bf16x8*)(&Wls[(wn * 64 + t * 16 + m16) * RS + q * 8]);
        }
#pragma unroll
        for (int mt = 0; mt < 4; mt++)
#pragma unroll
            for (int nt = 0; nt < 4; nt++)
                acc[mt][nt] = __builtin_amdgcn_mfma_f32_16x16x32_bf16(af[mt], bf[nt], acc[mt][nt], 0, 0, 0);
    }

    const bool g1 = (by >= NB0);
#pragma unroll
    for (int mt = 0; mt < 4; mt++) {
#pragma unroll
        for (int i = 0; i < 4; i++) {
            int row = m0 + wm * 64 + mt * 16 + q * 4 + i;
            if (row >= M) continue;
#pragma unroll
            for (int nt = 0; nt < 4; nt++) {
                int col = n0 + wn * 64 + nt * 16 + m16;
                float v = acc[mt][nt][i];
                if (!g1) {
                    v += bias[col];
                    v = fmaxf(v, 0.f);
                    out0[(size_t)row * s0 + col] = f2bf(v);
                } else {
                    out1[(size_t)row * 256 + (col - NB0 * 128)] = f2bf(v);
                }
            }
        }
    }
}

// ---------------- device: bf16-out GEMM tile (Hp / Hm) ----------------
template <int K, bool HASB, bool AF32>
__device__ void out_tile(ushort* Als, ushort* Wls, int tid, int bx, int by, int M,
                         const void* __restrict__ Av, const ushort* __restrict__ W,
                         const float* __restrict__ bias, ushort* __restrict__ out) {
    const int m0 = bx * 128, n0 = by * 128;
    const int lane = tid & 63, w = tid >> 6;
    const int wm = w >> 1, wn = w & 1;
    const int m16 = lane & 15, q = lane >> 4;

    f32x4 acc[4][4] = {};

    for (int k0 = 0; k0 < K; k0 += 32) {
        bf16x8 a_st[2], w_st[2];
#pragma unroll
        for (int r = 0; r < 2; r++) {
            int chunk = tid + r * 256;
            int row = chunk >> 2, off = (chunk & 3) * 8;
            int ga = min(m0 + row, M - 1);
            if constexpr (AF32) {
                const float* Af = (const float*)Av;
                float4 f0 = *(const float4*)(Af + (size_t)ga * K + k0 + off);
                float4 f1 = *(const float4*)(Af + (size_t)ga * K + k0 + off + 4);
                ushort4 u0 = f4bf(f0), u1 = f4bf(f1);
                bf16x8 av;
                av[0] = (short)u0.x; av[1] = (short)u0.y; av[2] = (short)u0.z; av[3] = (short)u0.w;
                av[4] = (short)u1.x; av[5] = (short)u1.y; av[6] = (short)u1.z; av[7] = (short)u1.w;
                a_st[r] = av;
            } else {
                a_st[r] = *(const bf16x8*)((const ushort*)Av + (size_t)ga * K + k0 + off);
            }
            w_st[r] = *(const bf16x8*)(W + (size_t)(n0 + row) * K + k0 + off);
        }
        __syncthreads();
#pragma unroll
        for (int r = 0; r < 2; r++) {
            int chunk = tid + r * 256;
            int row = chunk >> 2, off = (chunk & 3) * 8;
            *(bf16x8*)(&Als[row * RS + off]) = a_st[r];
            *(bf16x8*)(&Wls[row * RS + off]) = w_st[r];
        }
        __syncthreads();
        bf16x8 af[4], bf[4];
#pragma unroll
        for (int t = 0; t < 4; t++) {
            af[t] = *(const bf16x8*)(&Als[(wm * 64 + t * 16 + m16) * RS + q * 8]);
            bf[t] = *(const bf16x8*)(&Wls[(wn * 64 + t * 16 + m16) * RS + q * 8]);
        }
#pragma unroll
        for (int mt = 0; mt < 4; mt++)
#pragma unroll
            for (int nt = 0; nt < 4; nt++)
                acc[mt][nt] = __builtin_amdgcn_mfma_f32_16x16x32_bf16(af[mt], bf[nt], acc[mt][nt], 0, 0, 0);
    }

#pragma unroll
    for (int mt = 0; mt < 4; mt++) {
#pragma unroll
        for (int i = 0; i < 4; i++) {
            int row = m0 + wm * 64 + mt * 16 + q * 4 + i;
            if (row >= M) continue;
#pragma unroll
            for (int nt = 0; nt < 4; nt++) {
                int col = n0 + wn * 64 + nt * 16 + m16;
                float v = acc[mt][nt][i];
                if (HASB) v += bias[col];
                out[(size_t)row * 256 + col] = f2bf(v);
            }
        }
    }
}

// ---------------- merged prep + histogram kernel ----------------
__global__ __launch_bounds__(256) void preph_kernel(
    const int* __restrict__ dst_pm, const int* __restrict__ dst_mt,
    const int* __restrict__ pack_tcr,
    int* __restrict__ deg_pm, int* __restrict__ deg_mt, int* __restrict__ mark,
    const float4* __restrict__ Wr1f, ushort4* __restrict__ Wr1_b,
    const float4* __restrict__ Wr2f, ushort4* __restrict__ Wr2_b,
    const float* __restrict__ head_W1, ushort4* __restrict__ W1b_b, ushort4* __restrict__ W1c_b,
    const float* __restrict__ l1_pm_Wl, const float* __restrict__ l1_pm_Wr,
    const float* __restrict__ l1_mt_Wl, ushort* __restrict__ Wcat1_b,
    const float* __restrict__ l2_pm_Wl, const float* __restrict__ l2_pm_Wr,
    const float* __restrict__ l2_mt_Wl, ushort* __restrict__ Wcat2_b,
    const float4* __restrict__ emb_mhc, ushort* __restrict__ Acat1,
    const float* __restrict__ proj_W, const float* __restrict__ proj_b,
    ushort* __restrict__ Wcomp_b, float* __restrict__ bp) {
    __shared__ float red[128];
    const int b = blockIdx.x, tid = threadIdx.x;
    if (b < 2540) {
        int t = b * 256 + tid;
        if (t < EPM) atomicAdd(&deg_pm[dst_pm[t]], 1);
        else if (t < EPM + EMT) atomicAdd(&deg_mt[dst_mt[t - EPM]], 1);
        else if (t < EPM + EMT + BB) mark[pack_tcr[t - EPM - EMT]] = 1;  // benign race
    } else if (b < 2572) {
        int i = (b - 2540) * 256 + tid;
        if (i < 8192) Wr1_b[i] = f4bf(Wr1f[i]);
    } else if (b < 2636) {
        int i = (b - 2572) * 256 + tid;
        if (i < 16384) Wr2_b[i] = f4bf(Wr2f[i]);
    } else if (b < 2700) {
        int i = (b - 2636) * 256 + tid;
        if (i < 16384) {
            int n = i >> 6, k4 = (i & 63) * 4;
            W1b_b[i] = f4bf(*(const float4*)(head_W1 + (size_t)n * 768 + 256 + k4));
        }
    } else if (b < 2764) {
        int i = (b - 2700) * 256 + tid;
        if (i < 16384) {
            int n = i >> 6, k4 = (i & 63) * 4;
            W1c_b[i] = f4bf(*(const float4*)(head_W1 + (size_t)n * 768 + 512 + k4));
        }
    } else if (b < 3276) {
        int idx = (b - 2764) * 256 + tid;   // 512x256
        if (idx < 131072) {
            int r = idx >> 8, k = idx & 255;
            float v;
            if (r < 256) v = (k < 128) ? l1_pm_Wl[r * 128 + k] : l1_pm_Wr[r * 128 + (k - 128)];
            else         v = (k < 128) ? 0.f : l1_mt_Wl[(r - 256) * 128 + (k - 128)];
            Wcat1_b[idx] = f2bf(v);
        }
    } else if (b < 4044) {
        int idx = (b - 3276) * 256 + tid;   // 512x384
        if (idx < 196608) {
            int r = idx / 384, k = idx - r * 384;
            float v;
            if (r < 256) v = (k < 128) ? l2_pm_Wl[r * 128 + k] : l2_pm_Wr[r * 256 + (k - 128)];
            else         v = (k < 128) ? 0.f : l2_mt_Wl[(r - 256) * 256 + (k - 128)];
            Wcat2_b[idx] = f2bf(v);
        }
    } else if (b < 4669) {
        int i4 = (b - 4044) * 256 + tid;
        if (i4 < 160000) {
            int r = i4 >> 5, c4 = (i4 & 31) * 4;
            *(ushort4*)(Acat1 + (size_t)r * 256 + 128 + c4) = f4bf(emb_mhc[i4]);
        }
    } else {
        // wcomp: one block per output row i (0..255)
        int i = b - 4669;
        const float* w1row = head_W1 + (size_t)i * 768;
        if (tid < 128) {
            float acc = 0.f;
            for (int k = 0; k < 256; k++) acc += w1row[k] * proj_W[k * 128 + tid];
            Wcomp_b[i * 128 + tid] = f2bf(acc);
            red[tid] = w1row[2 * tid] * proj_b[2 * tid] + w1row[2 * tid + 1] * proj_b[2 * tid + 1];
        }
        __syncthreads();
        if (tid < 64) { red[tid] += red[tid + 64]; }
        __syncthreads();
        if (tid < 32) { red[tid] += red[tid + 32]; }
        __syncthreads();
        if (tid == 0) {
            float s = 0.f;
            for (int j = 0; j < 32; j++) s += red[j];
            bp[i] = s;
        }
    }
}

// ---------------- merged blocksum (raw partials) ----------------
__global__ __launch_bounds__(256) void blocksum2_kernel(const int* __restrict__ deg_pm,
                                                        const int* __restrict__ deg_mt,
                                                        const int* __restrict__ mark,
                                                        int* __restrict__ bsum_pm,
                                                        int* __restrict__ bsum_mt,
                                                        int* __restrict__ bsum_mk) {
    __shared__ int red[256];
    const int tid = threadIdx.x;
    const int* deg; int n, bi; int* bsum;
    if (blockIdx.x < 5) { deg = deg_pm; n = NMHC; bi = blockIdx.x; bsum = bsum_pm; }
    else if (blockIdx.x < 103) { deg = deg_mt; n = NTCR; bi = blockIdx.x - 5; bsum = bsum_mt; }
    else { deg = mark; n = NTCR; bi = blockIdx.x - 103; bsum = bsum_mk; }
    const int base = bi * 1024;
    int s = 0;
#pragma unroll
    for (int j = 0; j < 4; j++) {
        int i = base + tid + j * 256;
        if (i < n) s += deg[i];
    }
    red[tid] = s;
    __syncthreads();
    for (int off = 128; off > 0; off >>= 1) {
        if (tid < off) red[tid] += red[tid + off];
        __syncthreads();
    }
    if (tid == 0) bsum[bi] = red[0];
}

// ---------------- emit: rowptrs + compact list + inv map (inline exclusive base) ----------------
__global__ __launch_bounds__(256) void emit2_kernel(const int* __restrict__ deg_pm,
                                                    const int* __restrict__ deg_mt,
                                                    const int* __restrict__ mark,
                                                    const int* __restrict__ bsum_pm,
                                                    const int* __restrict__ bsum_mt,
                                                    const int* __restrict__ bsum_mk,
                                                    int* __restrict__ rp_pm,
                                                    int* __restrict__ rp_mt,
                                                    int* __restrict__ list,
                                                    int* __restrict__ inv,
                                                    int* __restrict__ nrows) {
    __shared__ int tsum[256];
    const int tid = threadIdx.x;
    const int* deg; const int* bsum; int* rp; int n, nb, bi, mode;
    if (blockIdx.x < 5) { deg = deg_pm; bsum = bsum_pm; rp = rp_pm; n = NMHC; nb = 5; bi = blockIdx.x; mode = 0; }
    else if (blockIdx.x < 103) { deg = deg_mt; bsum = bsum_mt; rp = rp_mt; n = NTCR; nb = 98; bi = blockIdx.x - 5; mode = 0; }
    else { deg = mark; bsum = bsum_mk; rp = nullptr; n = NTCR; nb = 98; bi = blockIdx.x - 103; mode = 1; }
    tsum[tid] = (tid < bi) ? bsum[tid] : 0;
    __syncthreads();
    for (int off = 128; off > 0; off >>= 1) {
        if (tid < off) tsum[tid] += tsum[tid + off];
        __syncthreads();
    }
    const int base = tsum[0];
    __syncthreads();
    const int i0 = bi * 1024 + tid * 4;
    int4 v = make_int4(0, 0, 0, 0);
    if (i0 + 3 < n) v = *(const int4*)(deg + i0);
    else if (i0 < n) {
        int t[4] = {0, 0, 0, 0};
        for (int j = 0; j < 4 && i0 + j < n; j++) t[j] = deg[i0 + j];
        v = make_int4(t[0], t[1], t[2], t[3]);
    }
    tsum[tid] = v.x + v.y + v.z + v.w;
    __syncthreads();
    for (int off = 1; off < 256; off <<= 1) {
        int t = (tid >= off) ? tsum[tid - off] : 0;
        __syncthreads();
        tsum[tid] += t;
        __syncthreads();
    }
    int ex = ((tid > 0) ? tsum[tid - 1] : 0) + base;
    if (mode == 0) {
        if (i0 + 3 < n) {
            int r1 = ex + v.x, r2 = r1 + v.y, r3 = r2 + v.z;
            *(int4*)(rp + i0) = make_int4(ex, r1, r2, r3);
        } else if (i0 < n) {
            int r = ex;
            int vv[4] = {v.x, v.y, v.z, v.w};
            for (int j = 0; j < 4 && i0 + j < n; j++) { rp[i0 + j] = r; r += vv[j]; }
        }
        if (bi == nb - 1 && tid == 255) rp[n] = base + tsum[255];
    } else {
        int p = ex;
        int vv[4] = {v.x, v.y, v.z, v.w};
#pragma unroll
        for (int j = 0; j < 4; j++) {
            if (i0 + j < n && vv[j]) { list[p] = i0 + j; inv[i0 + j] = p; p++; }
        }
        if (bi == nb - 1 && tid == 255) nrows[0] = base + tsum[255];
    }
}

// ---------------- merged CSR fill ----------------
__global__ void fill2_kernel(const int* __restrict__ src_pm, const int* __restrict__ dst_pm,
                             const int* __restrict__ src_mt, const int* __restrict__ dst_mt,
                             const int* __restrict__ rp_pm, int* __restrict__ cur_pm, int* __restrict__ csr_pm,
                             const int* __restrict__ rp_mt, int* __restrict__ cur_mt, int* __restrict__ csr_mt) {
    int t = blockIdx.x * blockDim.x + threadIdx.x;
    if (t < EPM) {
        int d = dst_pm[t];
        int pos = atomicAdd(&cur_pm[d], 1);
        csr_pm[rp_pm[d] + pos] = src_pm[t];
    } else if (t < EPM + EMT) {
        int t2 = t - EPM;
        int d = dst_mt[t2];
        int pos = atomicAdd(&cur_mt[d], 1);
        csr_mt[rp_mt[d] + pos] = src_mt[t2];
    }
}

// ---------------- merged: pm gather (shfl-parallel) + pt remap ----------------
__global__ __launch_bounds__(256) void gph_kernel(
    const int* __restrict__ rp, const int* __restrict__ csr_src,
    const float* __restrict__ X, ushort* __restrict__ A1, ushort* __restrict__ A2,
    const int* __restrict__ pack_tcr, const int* __restrict__ inv, int* __restrict__ pt_c) {
    const int tid = threadIdx.x;
    const int b = blockIdx.x;
    if (b < 625) {
        const int r = b * 8 + (tid >> 5);
        const int lane = tid & 31;
        if (r >= NMHC) return;
        const int e0 = rp[r], e1 = rp[r + 1];
        float4 s = make_float4(0.f, 0.f, 0.f, 0.f);
        for (int eb = e0; eb < e1; eb += 32) {
            int dc = min(32, e1 - eb);
            int sidx_l = (lane < dc) ? csr_src[eb + lane] : 0;
            for (int e = 0; e < dc; e++) {
                int sidx = __shfl(sidx_l, e, 32);
                float4 v = ((const float4*)(X + (long)sidx * 128))[lane];
                s.x += v.x; s.y += v.y; s.z += v.z; s.w += v.w;
            }
        }
        float sc = 1.f / fmaxf((float)(e1 - e0), 1.f);
        ushort4 o = make_ushort4(f2bf(s.x * sc), f2bf(s.y * sc), f2bf(s.z * sc), f2bf(s.w * sc));
        *(ushort4*)(A1 + (size_t)r * 256 + lane * 4) = o;
        *(ushort4*)(A2 + (size_t)r * 384 + lane * 4) = o;
    } else {
        int i = (b - 625) * 256 + tid;
        if (i < BB) pt_c[i] = inv[pack_tcr[i]];
    }
}

// ---------------- mhc fused GEMM launch + Hp tiles ----------------
template <int K>
__global__ __launch_bounds__(256, 2) void fusedhp_kernel(
    int M, const ushort* __restrict__ A, const ushort* __restrict__ W,
    const float* __restrict__ bias,
    ushort* __restrict__ out0, int s0, ushort* __restrict__ out1,
    int hpBy, const float* __restrict__ emb_pep, const ushort* __restrict__ Wcomp,
    const float* __restrict__ bp, ushort* __restrict__ Hp) {
    __shared__ ushort Als[128 * RS];
    __shared__ ushort Wls[128 * RS];
    const int tid = threadIdx.x;
    const int b = blockIdx.x;
    if (b < 160)
        fused_tile<K, 2>(Als, Wls, tid, b % 40, b / 40, M, A, W, bias, out0, s0, out1);
    else
        out_tile<128, true, true>(Als, Wls, tid, b - 160, hpBy, NPEP, emb_pep, Wcomp, bp, Hp);
}

// ---------------- fused TCR chain (2-buffer LDS + reg-held A2, 4 blocks/CU) + Hm ----------------
__global__ __launch_bounds__(256, 4) void tcrhm_kernel(
    const int* __restrict__ nrowsp, const int* __restrict__ list,
    const int* __restrict__ rp, const int* __restrict__ csr_src,
    const ushort* __restrict__ Z1, const ushort* __restrict__ Z2,
    const float* __restrict__ emb_tcr,
    const ushort* __restrict__ Wr1, const ushort* __restrict__ Wr2,
    const ushort* __restrict__ W1c,
    const float* __restrict__ bl1, const float* __restrict__ bl2,
    ushort* __restrict__ Ht_c,
    const ushort* __restrict__ mhc2, const ushort* __restrict__ W1b,
    ushort* __restrict__ Hm) {
    union SM {
        struct { ushort B[32 * RS2]; ushort A[32 * RS2]; } t;                       // 33792 B
        struct { ushort Als[128 * RS]; ushort Wls[128 * RS]; } g;                   // 20480 B
    };
    __shared__ SM sm;
    const int tid = threadIdx.x;

    if (blockIdx.x >= 1563) {
        int v = blockIdx.x - 1563;             // 0..79
        out_tile<256, false, false>(sm.g.Als, sm.g.Wls, tid, v % 40, v / 40, NMHC,
                                    mhc2, W1b, nullptr, Hm);
        return;
    }

    const int M = nrowsp[0];
    const int m0 = blockIdx.x * 32;
    if (m0 >= M) return;
    const int lane = tid & 63, w = tid >> 6;   // wave w: cols w*64..w*64+63
    const int m16 = lane & 15, q = lane >> 4;

    // ---- stage 0: emb_tcr rows f32->bf16 -> B (RS1) ----
#pragma unroll
    for (int r = 0; r < 4; r++) {
        int chunk = tid + r * 256;             // 1024 chunks: 32 rows x 32 float4
        int row = chunk >> 5, c4 = (chunk & 31) * 4;
        int grow = list[min(m0 + row, M - 1)];
        float4 v = *(const float4*)(emb_tcr + (size_t)grow * 128 + c4);
        *(ushort4*)(&sm.t.B[row * RS1 + c4]) = f4bf(v);
    }

    // ---- SINGLE gather walk: dual Z loads; A1 mean -> LDS A; A2 mean -> registers ----
    float a2r[4][8];
    {
        const int g = tid >> 5, gl = tid & 31;
#pragma unroll
        for (int ri = 0; ri < 4; ri++) {       // static ri -> a2r stays in VGPRs
            int rr = g + ri * 8;
            int cr = min(m0 + rr, M - 1);
            int orig = list[cr];
            int e0 = rp[orig], e1 = rp[orig + 1];
            int deg = e1 - e0;
            float s1[8] = {}, s2[8] = {};
            for (int eb = e0; eb < e1; eb += 32) {
                int dc = min(32, e1 - eb);
                int sidx_l = (gl < dc) ? csr_src[eb + gl] : 0;
                for (int e = 0; e < dc; e++) {
                    int sidx = __shfl(sidx_l, e, 32);
                    uint4 u1 = *(const uint4*)(Z1 + (size_t)sidx * 256 + gl * 8);
                    uint4 u2 = *(const uint4*)(Z2 + (size_t)sidx * 256 + gl * 8);
                    float x, y;
                    bf2x2(u1.x, x, y); s1[0] += x; s1[1] += y;
                    bf2x2(u1.y, x, y); s1[2] += x; s1[3] += y;
                    bf2x2(u1.z, x, y); s1[4] += x; s1[5] += y;
                    bf2x2(u1.w, x, y); s1[6] += x; s1[7] += y;
                    bf2x2(u2.x, x, y); s2[0] += x; s2[1] += y;
                    bf2x2(u2.y, x, y); s2[2] += x; s2[3] += y;
                    bf2x2(u2.z, x, y); s2[4] += x; s2[5] += y;
                    bf2x2(u2.w, x, y); s2[6] += x; s2[7] += y;
                }
            }
            float es = 1.f / fmaxf((float)deg, 1.f);
            uint4 w1;
            w1.x = (unsigned)f2bf(s1[0] * es) | ((unsigned)f2bf(s1[1] * es) << 16);
            w1.y = (unsigned)f2bf(s1[2] * es) | ((unsigned)f2bf(s1[3] * es) << 16);
            w1.z = (unsigned)f2bf(s1[4] * es) | ((unsigned)f2bf(s1[5] * es) << 16);
            w1.w = (unsigned)f2bf(s1[6] * es) | ((unsigned)f2bf(s1[7] * es) << 16);
            *(uint4*)(&sm.t.A[rr * RS2 + gl * 8]) = w1;
#pragma unroll
            for (int j = 0; j < 8; j++) a2r[ri][j] = s2[j] * es;
        }
    }
    __syncthreads();

    // ---- stage 1a: T1 = relu(etc @ Wr1^T + bl1 + A) ----
    {
        f32x4 acc[2][4] = {};
        for (int k0 = 0; k0 < 128; k0 += 32) {
            bf16x8 af[2], bf[4];
#pragma unroll
            for (int t = 0; t < 2; t++)
                af[t] = *(const bf16x8*)(&sm.t.B[(t * 16 + m16) * RS1 + k0 + q * 8]);
#pragma unroll
            for (int t = 0; t < 4; t++)
                bf[t] = *(const bf16x8*)(Wr1 + (size_t)(w * 64 + t * 16 + m16) * 128 + k0 + q * 8);
#pragma unroll
            for (int mt = 0; mt < 2; mt++)
#pragma unroll
                for (int nt = 0; nt < 4; nt++)
                    acc[mt][nt] = __builtin_amdgcn_mfma_f32_16x16x32_bf16(af[mt], bf[nt], acc[mt][nt], 0, 0, 0);
        }
        __syncthreads();                       // B reads done before rewrite
#pragma unroll
        for (int mt = 0; mt < 2; mt++)
#pragma unroll
            for (int i = 0; i < 4; i++) {
                int lr = mt * 16 + q * 4 + i;
#pragma unroll
                for (int nt = 0; nt < 4; nt++) {
                    int col = w * 64 + nt * 16 + m16;
                    float v = acc[mt][nt][i] + bl1[col] + bf2f(sm.t.A[lr * RS2 + col]);
                    sm.t.B[lr * RS2 + col] = f2bf(fmaxf(v, 0.f));
                }
            }
    }
    __syncthreads();                           // A (Z1-mean) fully consumed

    // ---- dump reg-held A2 means into A buffer ----
    {
        const int g = tid >> 5, gl = tid & 31;
#pragma unroll
        for (int ri = 0; ri < 4; ri++) {
            int rr = g + ri * 8;
            uint4 w2;
            w2.x = (unsigned)f2bf(a2r[ri][0]) | ((unsigned)f2bf(a2r[ri][1]) << 16);
            w2.y = (unsigned)f2bf(a2r[ri][2]) | ((unsigned)f2bf(a2r[ri][3]) << 16);
            w2.z = (unsigned)f2bf(a2r[ri][4]) | ((unsigned)f2bf(a2r[ri][5]) << 16);
            w2.w = (unsigned)f2bf(a2r[ri][6]) | ((unsigned)f2bf(a2r[ri][7]) << 16);
            *(uint4*)(&sm.t.A[rr * RS2 + gl * 8]) = w2;
        }
    }
    __syncthreads();

    // ---- stage 1b: T = relu(T1 @ Wr2^T + bl2 + A) ----
    {
        f32x4 acc[2][4] = {};
        for (int k0 = 0; k0 < 256; k0 += 32) {
            bf16x8 af[2], bf[4];
#pragma unroll
            for (int t = 0; t < 2; t++)
                af[t] = *(const bf16x8*)(&sm.t.B[(t * 16 + m16) * RS2 + k0 + q * 8]);
#pragma unroll
            for (int t = 0; t < 4; t++)
                bf[t] = *(const bf16x8*)(Wr2 + (size_t)(w * 64 + t * 16 + m16) * 256 + k0 + q * 8);
#pragma unroll
            for (int mt = 0; mt < 2; mt++)
#pragma unroll
                for (int nt = 0; nt < 4; nt++)
                    acc[mt][nt] = __builtin_amdgcn_mfma_f32_16x16x32_bf16(af[mt], bf[nt], acc[mt][nt], 0, 0, 0);
        }
        __syncthreads();
#pragma unroll
        for (int mt = 0; mt < 2; mt++)
#pragma unroll
            for (int i = 0; i < 4; i++) {
                int lr = mt * 16 + q * 4 + i;
#pragma unroll
                for (int nt = 0; nt < 4; nt++) {
                    int col = w * 64 + nt * 16 + m16;
                    float v = acc[mt][nt][i] + bl2[col] + bf2f(sm.t.A[lr * RS2 + col]);
                    sm.t.B[lr * RS2 + col] = f2bf(fmaxf(v, 0.f));
                }
            }
    }
    __syncthreads();

    // ---- stage 2: Ht_tile = T @ W1c^T -> B ----
    {
        f32x4 acc[2][4] = {};
        for (int k0 = 0; k0 < 256; k0 += 32) {
            bf16x8 af[2], bf[4];
#pragma unroll
            for (int t = 0; t < 2; t++)
                af[t] = *(const bf16x8*)(&sm.t.B[(t * 16 + m16) * RS2 + k0 + q * 8]);
#pragma unroll
            for (int t = 0; t < 4; t++)
                bf[t] = *(const bf16x8*)(W1c + (size_t)(w * 64 + t * 16 + m16) * 256 + k0 + q * 8);
#pragma unroll
            for (int mt = 0; mt < 2; mt++)
#pragma unroll
                for (int nt = 0; nt < 4; nt++)
                    acc[mt][nt] = __builtin_amdgcn_mfma_f32_16x16x32_bf16(af[mt], bf[nt], acc[mt][nt], 0, 0, 0);
        }
        __syncthreads();
#pragma unroll
        for (int mt = 0; mt < 2; mt++)
#pragma unroll
            for (int i = 0; i < 4; i++) {
                int lr = mt * 16 + q * 4 + i;
#pragma unroll
                for (int nt = 0; nt < 4; nt++) {
                    int col = w * 64 + nt * 16 + m16;
                    sm.t.B[lr * RS2 + col] = f2bf(acc[mt][nt][i]);
                }
            }
    }
    __syncthreads();

    // coalesced COMPACT writeback
#pragma unroll
    for (int r = 0; r < 4; r++) {
        int chunk = tid + r * 256;
        int row = chunk >> 5, c8 = (chunk & 31) * 8;
        if (m0 + row < M)
            *(uint4*)(Ht_c + (size_t)(m0 + row) * 256 + c8) = *(const uint4*)(&sm.t.B[row * RS2 + c8]);
    }
}

// ---------------- combine ----------------
__global__ __launch_bounds__(256) void combine_kernel(
    const ushort* __restrict__ Hp, const ushort* __restrict__ Hm, const ushort* __restrict__ Ht,
    const int* __restrict__ pp, const int* __restrict__ pm, const int* __restrict__ pt_c,
    const float* __restrict__ b1, const float* __restrict__ W2, const float* __restrict__ b2,
    float* __restrict__ out) {
    const int tid = threadIdx.x;
    const int lane = tid & 63, w = tid >> 6;
    const int c = lane * 4;
    const float4 b1v = *(const float4*)(b1 + c);
    const float4 w2v = *(const float4*)(W2 + c);
    const float b2v = b2[0];
    const int base = blockIdx.x * 32 + w * 8;
#pragma unroll
    for (int t = 0; t < 8; t++) {
        int i = base + t;
        if (i >= BB) return;
        int ra = pp[i], rb = pm[i], rc = pt_c[i];
        ushort4 ua = *(const ushort4*)(Hp + (size_t)ra * 256 + c);
        ushort4 ub = *(const ushort4*)(Hm + (size_t)rb * 256 + c);
        ushort4 uc = *(const ushort4*)(Ht + (size_t)rc * 256 + c);
        float h0 = fmaxf(bf2f(ua.x) + bf2f(ub.x) + bf2f(uc.x) + b1v.x, 0.f);
        float h1 = fmaxf(bf2f(ua.y) + bf2f(ub.y) + bf2f(uc.y) + b1v.y, 0.f);
        float h2 = fmaxf(bf2f(ua.z) + bf2f(ub.z) + bf2f(uc.z) + b1v.z, 0.f);
        float h3 = fmaxf(bf2f(ua.w) + bf2f(ub.w) + bf2f(uc.w) + b1v.w, 0.f);
        float p = h0 * w2v.x + h1 * w2v.y + h2 * w2v.z + h3 * w2v.w;
#pragma unroll
        for (int off = 32; off > 0; off >>= 1) p += __shfl_down(p, off);
        if (lane == 0) out[i] = p + b2v;
    }
}

// ---------------- launch ----------------
extern "C" void kernel_launch(void* const* d_in, const int* in_sizes, int n_in,
                              void* d_out, int out_size, void* d_ws, size_t ws_size,
                              hipStream_t stream) {
    const float* emb_pep = (const float*)d_in[0];
    const float* emb_mhc = (const float*)d_in[1];
    const float* emb_tcr = (const float*)d_in[2];
    const int* src_pm = (const int*)d_in[3];
    const int* dst_pm = (const int*)d_in[4];
    const int* src_mt = (const int*)d_in[5];
    const int* dst_mt = (const int*)d_in[6];
    const int* pack_pep = (const int*)d_in[7];
    const int* pack_mhc = (const int*)d_in[8];
    const int* pack_tcr = (const int*)d_in[9];
    const float* l1_pm_Wl = (const float*)d_in[10];
    const float* l1_pm_bl = (const float*)d_in[11];
    const float* l1_pm_Wr = (const float*)d_in[12];
    const float* l1_mt_Wl = (const float*)d_in[13];
    const float* l1_mt_bl = (const float*)d_in[14];
    const float* l1_mt_Wr = (const float*)d_in[15];
    const float* l2_pm_Wl = (const float*)d_in[16];
    const float* l2_pm_bl = (const float*)d_in[17];
    const float* l2_pm_Wr = (const float*)d_in[18];
    const float* l2_mt_Wl = (const float*)d_in[19];
    const float* l2_mt_bl = (const float*)d_in[20];
    const float* l2_mt_Wr = (const float*)d_in[21];
    const float* proj_W = (const float*)d_in[22];
    const float* proj_b = (const float*)d_in[23];
    const float* head_W1 = (const float*)d_in[24];
    const float* head_b1 = (const float*)d_in[25];
    const float* head_W2 = (const float*)d_in[26];
    const float* head_b2 = (const float*)d_in[27];
    float* out = (float*)d_out;

    // ---------------- workspace layout ----------------
    int* ib = (int*)d_ws;
    int* deg_pm = ib;                 // 5000
    int* cur_pm = ib + 5000;          // 5000
    int* deg_mt = ib + 10000;         // 100000
    int* cur_mt = ib + 110000;        // 100000
    int* mark   = ib + 210000;        // 100000  [zero region: first 310000 ints, via memset]
    int* rp_pm  = ib + 310000;        // 5001 (pad 5008)
    int* rp_mt  = ib + 315008;        // 100001 (pad 100008)
    int* csr_pm = ib + 415016;        // 200000
    int* csr_mt = ib + 615016;        // 400000
    int* bsum_pm = ib + 1015016;      // 160
    int* bsum_mt = ib + 1015176;      // 160
    int* bsum_mk = ib + 1015336;      // 160
    int* nrows   = ib + 1015496;      // 8
    int* list    = ib + 1015504;      // 50048 -> 1065552
    int* inv     = ib + 1065552;      // 100000 -> 1165552
    int* pt_c    = ib + 1165552;      // 50048 -> 1215600

    float* f = (float*)(ib + 1215600);
    float* bp = f;                    // 256

    ushort* u = (ushort*)(f + 256);
    ushort* Wcat1_b = u;              // 131072
    ushort* Wcat2_b = u + 131072;     // 196608
    ushort* W1b_b   = u + 327680;     // 65536
    ushort* W1c_b   = u + 393216;     // 65536
    ushort* Wcomp_b = u + 458752;     // 32768
    ushort* Wr1_b   = u + 491520;     // 32768
    ushort* Wr2_b   = u + 524288;     // 65536
    ushort* Acat1   = u + 589824;     // 1280000
    ushort* Acat2   = u + 1869824;    // 1920000
    ushort* Zb1     = u + 3789824;    // 1280000
    ushort* Zb2     = u + 5069824;    // 1280000
    ushort* mhc2_b  = u + 6349824;    // 1280000
    ushort* Hp_b    = u + 7629824;    // 5120000
    ushort* Hm_b    = u + 12749824;   // 1280000
    ushort* Ht_c    = u + 14029824;   // 12800000 (50000x256 compact)

    // 0. zero deg/cur/mark (stream-ordered DMA)
    hipMemsetAsync(ib, 0, 310000 * sizeof(int), stream);

    // 1. merged prep + histogram
    preph_kernel<<<4925, 256, 0, stream>>>(
        dst_pm, dst_mt, pack_tcr, deg_pm, deg_mt, mark,
        (const float4*)l1_mt_Wr, (ushort4*)Wr1_b,
        (const float4*)l2_mt_Wr, (ushort4*)Wr2_b,
        head_W1, (ushort4*)W1b_b, (ushort4*)W1c_b,
        l1_pm_Wl, l1_pm_Wr, l1_mt_Wl, Wcat1_b,
        l2_pm_Wl, l2_pm_Wr, l2_mt_Wl, Wcat2_b,
        (const float4*)emb_mhc, Acat1,
        proj_W, proj_b, Wcomp_b, bp);

    // 2-4. CSR build + compaction
    blocksum2_kernel<<<201, 256, 0, stream>>>(deg_pm, deg_mt, mark, bsum_pm, bsum_mt, bsum_mk);
    emit2_kernel<<<201, 256, 0, stream>>>(deg_pm, deg_mt, mark, bsum_pm, bsum_mt, bsum_mk,
                                          rp_pm, rp_mt, list, inv, nrows);
    fill2_kernel<<<(EPM + EMT + 255) / 256, 256, 0, stream>>>(
        src_pm, dst_pm, src_mt, dst_mt, rp_pm, cur_pm, csr_pm, rp_mt, cur_mt, csr_mt);

    // 5. pm gather + pt remap
    gph_kernel<<<821, 256, 0, stream>>>(
        rp_pm, csr_pm, emb_pep, Acat1, Acat2, pack_tcr, inv, pt_c);

    // 6-7. mhc layers + Hp halves
    fusedhp_kernel<256><<<317, 256, 0, stream>>>(
        NMHC, Acat1, Wcat1_b, l1_pm_bl, Acat2 + 128, 384, Zb1,
        0, emb_pep, Wcomp_b, bp, Hp_b);
    fusedhp_kernel<384><<<317, 256, 0, stream>>>(
        NMHC, Acat2, Wcat2_b, l2_pm_bl, mhc2_b, 256, Zb2,
        1, emb_pep, Wcomp_b, bp, Hp_b);

    // 8. fused tcr chain (compact Ht) + Hm tiles
    tcrhm_kernel<<<1563 + 80, 256, 0, stream>>>(
        nrows, list, rp_mt, csr_mt, Zb1, Zb2, emb_tcr,
        Wr1_b, Wr2_b, W1c_b, l1_mt_bl, l2_mt_bl, Ht_c,
        mhc2_b, W1b_b, Hm_b);

    // 9. combine
    combine_kernel<<<(BB + 31) / 32, 256, 0, stream>>>(
        Hp_b, Hm_b, Ht_c, pack_pep, pack_mhc, pt_c,
        head_b1, head_W2, head_b2, out);
}

// Round 11
// 372.674 us; speedup vs baseline: 1.0517x; 1.0380x over previous
//
#include <hip/hip_runtime.h>

// ---------------- problem constants ----------------
constexpr int NPEP = 20000, NMHC = 5000, NTCR = 100000;
constexpr int EPM = 200000, EMT = 400000, BB = 50000;
constexpr int MAXU = 50000;

typedef __attribute__((ext_vector_type(8))) short bf16x8;
typedef __attribute__((ext_vector_type(4))) float f32x4;

__device__ inline ushort f2bf(float x) {
    union { float f; unsigned u; } v; v.f = x;
    unsigned r = (v.u + 0x7FFF + ((v.u >> 16) & 1)) >> 16;
    return (ushort)r;
}
__device__ inline float bf2f(ushort b) {
    union { unsigned u; float f; } t; t.u = ((unsigned)b) << 16; return t.f;
}
__device__ inline void bf2x2(unsigned u, float& a, float& b) {
    union { unsigned x; float f; } t1, t2;
    t1.x = u << 16; t2.x = u & 0xffff0000u;
    a = t1.f; b = t2.f;
}
__device__ inline ushort4 f4bf(float4 v) {
    return make_ushort4(f2bf(v.x), f2bf(v.y), f2bf(v.z), f2bf(v.w));
}

constexpr int RS  = 40;    // mfma LDS row stride
constexpr int RS1 = 136;   // tcr etc tile stride (K=128)
constexpr int RS2 = 264;   // tcr 256-col tile stride

// ---------------- device: dual-output fused GEMM tile (mhc layers) ----------------
template <int K, int NB0>
__device__ void fused_tile(ushort* Als, ushort* Wls, int tid, int bx, int by, int M,
                           const ushort* __restrict__ A, const ushort* __restrict__ W,
                           const float* __restrict__ bias,
                           ushort* __restrict__ out0, int s0, ushort* __restrict__ out1) {
    const int m0 = bx * 128, n0 = by * 128;
    const int lane = tid & 63, w = tid >> 6;
    const int wm = w >> 1, wn = w & 1;
    const int m16 = lane & 15, q = lane >> 4;

    f32x4 acc[4][4] = {};

    for (int k0 = 0; k0 < K; k0 += 32) {
        bf16x8 a_st[2], w_st[2];
#pragma unroll
        for (int r = 0; r < 2; r++) {
            int chunk = tid + r * 256;
            int row = chunk >> 2, off = (chunk & 3) * 8;
            int ga = min(m0 + row, M - 1);
            a_st[r] = *(const bf16x8*)(A + (size_t)ga * K + k0 + off);
            w_st[r] = *(const bf16x8*)(W + (size_t)(n0 + row) * K + k0 + off);
        }
        __syncthreads();
#pragma unroll
        for (int r = 0; r < 2; r++) {
            int chunk = tid + r * 256;
            int row = chunk >> 2, off = (chunk & 3) * 8;
            *(bf16x8*)(&Als[row * RS + off]) = a_st[r];
            *(bf16x8*)(&Wls[row * RS + off]) = w_st[r];
        }
        __syncthreads();
        bf16x8 af[4], bf[4];
#pragma unroll
        for (int t = 0; t < 4; t++) {
            af[t] = *(const bf16x8*)(&Als[(wm * 64 + t * 16 + m16) * RS + q * 8]);
            bf[t] = *(const bf16x8*)(&Wls[(wn * 64 + t * 16 + m16) * RS + q * 8]);
        }
#pragma unroll
        for (int mt = 0; mt < 4; mt++)
#pragma unroll
            for (int nt = 0; nt < 4; nt++)
                acc[mt][nt] = __builtin_amdgcn_mfma_f32_16x16x32_bf16(af[mt], bf[nt], acc[mt][nt], 0, 0, 0);
    }

    const bool g1 = (by >= NB0);
#pragma unroll
    for (int mt = 0; mt < 4; mt++) {
#pragma unroll
        for (int i = 0; i < 4; i++) {
            int row = m0 + wm * 64 + mt * 16 + q * 4 + i;
            if (row >= M) continue;
#pragma unroll
            for (int nt = 0; nt < 4; nt++) {
                int col = n0 + wn * 64 + nt * 16 + m16;
                float v = acc[mt][nt][i];
                if (!g1) {
                    v += bias[col];
                    v = fmaxf(v, 0.f);
                    out0[(size_t)row * s0 + col] = f2bf(v);
                } else {
                    out1[(size_t)row * 256 + (col - NB0 * 128)] = f2bf(v);
                }
            }
        }
    }
}

// ---------------- device: bf16-out GEMM tile (Hp / Hm) ----------------
template <int K, bool HASB, bool AF32>
__device__ void out_tile(ushort* Als, ushort* Wls, int tid, int bx, int by, int M,
                         const void* __restrict__ Av, const ushort* __restrict__ W,
                         const float* __restrict__ bias, ushort* __restrict__ out) {
    const int m0 = bx * 128, n0 = by * 128;
    const int lane = tid & 63, w = tid >> 6;
    const int wm = w >> 1, wn = w & 1;
    const int m16 = lane & 15, q = lane >> 4;

    f32x4 acc[4][4] = {};

    for (int k0 = 0; k0 < K; k0 += 32) {
        bf16x8 a_st[2], w_st[2];
#pragma unroll
        for (int r = 0; r < 2; r++) {
            int chunk = tid + r * 256;
            int row = chunk >> 2, off = (chunk & 3) * 8;
            int ga = min(m0 + row, M - 1);
            if constexpr (AF32) {
                const float* Af = (const float*)Av;
                float4 f0 = *(const float4*)(Af + (size_t)ga * K + k0 + off);
                float4 f1 = *(const float4*)(Af + (size_t)ga * K + k0 + off + 4);
                ushort4 u0 = f4bf(f0), u1 = f4bf(f1);
                bf16x8 av;
                av[0] = (short)u0.x; av[1] = (short)u0.y; av[2] = (short)u0.z; av[3] = (short)u0.w;
                av[4] = (short)u1.x; av[5] = (short)u1.y; av[6] = (short)u1.z; av[7] = (short)u1.w;
                a_st[r] = av;
            } else {
                a_st[r] = *(const bf16x8*)((const ushort*)Av + (size_t)ga * K + k0 + off);
            }
            w_st[r] = *(const bf16x8*)(W + (size_t)(n0 + row) * K + k0 + off);
        }
        __syncthreads();
#pragma unroll
        for (int r = 0; r < 2; r++) {
            int chunk = tid + r * 256;
            int row = chunk >> 2, off = (chunk & 3) * 8;
            *(bf16x8*)(&Als[row * RS + off]) = a_st[r];
            *(bf16x8*)(&Wls[row * RS + off]) = w_st[r];
        }
        __syncthreads();
        bf16x8 af[4], bf[4];
#pragma unroll
        for (int t = 0; t < 4; t++) {
            af[t] = *(const bf16x8*)(&Als[(wm * 64 + t * 16 + m16) * RS + q * 8]);
            bf[t] = *(const bf16x8*)(&Wls[(wn * 64 + t * 16 + m16) * RS + q * 8]);
        }
#pragma unroll
        for (int mt = 0; mt < 4; mt++)
#pragma unroll
            for (int nt = 0; nt < 4; nt++)
                acc[mt][nt] = __builtin_amdgcn_mfma_f32_16x16x32_bf16(af[mt], bf[nt], acc[mt][nt], 0, 0, 0);
    }

#pragma unroll
    for (int mt = 0; mt < 4; mt++) {
#pragma unroll
        for (int i = 0; i < 4; i++) {
            int row = m0 + wm * 64 + mt * 16 + q * 4 + i;
            if (row >= M) continue;
#pragma unroll
            for (int nt = 0; nt < 4; nt++) {
                int col = n0 + wn * 64 + nt * 16 + m16;
                float v = acc[mt][nt][i];
                if (HASB) v += bias[col];
                out[(size_t)row * 256 + col] = f2bf(v);
            }
        }
    }
}

// ---------------- merged prep + histogram kernel ----------------
__global__ __launch_bounds__(256) void preph_kernel(
    const int* __restrict__ dst_pm, const int* __restrict__ dst_mt,
    const int* __restrict__ pack_tcr,
    int* __restrict__ deg_pm, int* __restrict__ deg_mt, int* __restrict__ mark,
    const float4* __restrict__ Wr1f, ushort4* __restrict__ Wr1_b,
    const float4* __restrict__ Wr2f, ushort4* __restrict__ Wr2_b,
    const float* __restrict__ head_W1, ushort4* __restrict__ W1b_b, ushort4* __restrict__ W1c_b,
    const float* __restrict__ l1_pm_Wl, const float* __restrict__ l1_pm_Wr,
    const float* __restrict__ l1_mt_Wl, ushort* __restrict__ Wcat1_b,
    const float* __restrict__ l2_pm_Wl, const float* __restrict__ l2_pm_Wr,
    const float* __restrict__ l2_mt_Wl, ushort* __restrict__ Wcat2_b,
    const float4* __restrict__ emb_mhc, ushort* __restrict__ Acat1,
    const float* __restrict__ proj_W, const float* __restrict__ proj_b,
    ushort* __restrict__ Wcomp_b, float* __restrict__ bp) {
    __shared__ float red[128];
    const int b = blockIdx.x, tid = threadIdx.x;
    if (b < 2540) {
        int t = b * 256 + tid;
        if (t < EPM) atomicAdd(&deg_pm[dst_pm[t]], 1);
        else if (t < EPM + EMT) atomicAdd(&deg_mt[dst_mt[t - EPM]], 1);
        else if (t < EPM + EMT + BB) mark[pack_tcr[t - EPM - EMT]] = 1;  // benign race
    } else if (b < 2572) {
        int i = (b - 2540) * 256 + tid;
        if (i < 8192) Wr1_b[i] = f4bf(Wr1f[i]);
    } else if (b < 2636) {
        int i = (b - 2572) * 256 + tid;
        if (i < 16384) Wr2_b[i] = f4bf(Wr2f[i]);
    } else if (b < 2700) {
        int i = (b - 2636) * 256 + tid;
        if (i < 16384) {
            int n = i >> 6, k4 = (i & 63) * 4;
            W1b_b[i] = f4bf(*(const float4*)(head_W1 + (size_t)n * 768 + 256 + k4));
        }
    } else if (b < 2764) {
        int i = (b - 2700) * 256 + tid;
        if (i < 16384) {
            int n = i >> 6, k4 = (i & 63) * 4;
            W1c_b[i] = f4bf(*(const float4*)(head_W1 + (size_t)n * 768 + 512 + k4));
        }
    } else if (b < 3276) {
        int idx = (b - 2764) * 256 + tid;   // 512x256
        if (idx < 131072) {
            int r = idx >> 8, k = idx & 255;
            float v;
            if (r < 256) v = (k < 128) ? l1_pm_Wl[r * 128 + k] : l1_pm_Wr[r * 128 + (k - 128)];
            else         v = (k < 128) ? 0.f : l1_mt_Wl[(r - 256) * 128 + (k - 128)];
            Wcat1_b[idx] = f2bf(v);
        }
    } else if (b < 4044) {
        int idx = (b - 3276) * 256 + tid;   // 512x384
        if (idx < 196608) {
            int r = idx / 384, k = idx - r * 384;
            float v;
            if (r < 256) v = (k < 128) ? l2_pm_Wl[r * 128 + k] : l2_pm_Wr[r * 256 + (k - 128)];
            else         v = (k < 128) ? 0.f : l2_mt_Wl[(r - 256) * 256 + (k - 128)];
            Wcat2_b[idx] = f2bf(v);
        }
    } else if (b < 4669) {
        int i4 = (b - 4044) * 256 + tid;
        if (i4 < 160000) {
            int r = i4 >> 5, c4 = (i4 & 31) * 4;
            *(ushort4*)(Acat1 + (size_t)r * 256 + 128 + c4) = f4bf(emb_mhc[i4]);
        }
    } else {
        // wcomp: one block per output row i (0..255)
        int i = b - 4669;
        const float* w1row = head_W1 + (size_t)i * 768;
        if (tid < 128) {
            float acc = 0.f;
            for (int k = 0; k < 256; k++) acc += w1row[k] * proj_W[k * 128 + tid];
            Wcomp_b[i * 128 + tid] = f2bf(acc);
            red[tid] = w1row[2 * tid] * proj_b[2 * tid] + w1row[2 * tid + 1] * proj_b[2 * tid + 1];
        }
        __syncthreads();
        if (tid < 64) { red[tid] += red[tid + 64]; }
        __syncthreads();
        if (tid < 32) { red[tid] += red[tid + 32]; }
        __syncthreads();
        if (tid == 0) {
            float s = 0.f;
            for (int j = 0; j < 32; j++) s += red[j];
            bp[i] = s;
        }
    }
}

// ---------------- merged blocksum (raw partials) ----------------
__global__ __launch_bounds__(256) void blocksum2_kernel(const int* __restrict__ deg_pm,
                                                        const int* __restrict__ deg_mt,
                                                        const int* __restrict__ mark,
                                                        int* __restrict__ bsum_pm,
                                                        int* __restrict__ bsum_mt,
                                                        int* __restrict__ bsum_mk) {
    __shared__ int red[256];
    const int tid = threadIdx.x;
    const int* deg; int n, bi; int* bsum;
    if (blockIdx.x < 5) { deg = deg_pm; n = NMHC; bi = blockIdx.x; bsum = bsum_pm; }
    else if (blockIdx.x < 103) { deg = deg_mt; n = NTCR; bi = blockIdx.x - 5; bsum = bsum_mt; }
    else { deg = mark; n = NTCR; bi = blockIdx.x - 103; bsum = bsum_mk; }
    const int base = bi * 1024;
    int s = 0;
#pragma unroll
    for (int j = 0; j < 4; j++) {
        int i = base + tid + j * 256;
        if (i < n) s += deg[i];
    }
    red[tid] = s;
    __syncthreads();
    for (int off = 128; off > 0; off >>= 1) {
        if (tid < off) red[tid] += red[tid + off];
        __syncthreads();
    }
    if (tid == 0) bsum[bi] = red[0];
}

// ---------------- emit: rowptrs + compact list + inv map (inline exclusive base) ----------------
__global__ __launch_bounds__(256) void emit2_kernel(const int* __restrict__ deg_pm,
                                                    const int* __restrict__ deg_mt,
                                                    const int* __restrict__ mark,
                                                    const int* __restrict__ bsum_pm,
                                                    const int* __restrict__ bsum_mt,
                                                    const int* __restrict__ bsum_mk,
                                                    int* __restrict__ rp_pm,
                                                    int* __restrict__ rp_mt,
                                                    int* __restrict__ list,
                                                    int* __restrict__ inv,
                                                    int* __restrict__ nrows) {
    __shared__ int tsum[256];
    const int tid = threadIdx.x;
    const int* deg; const int* bsum; int* rp; int n, nb, bi, mode;
    if (blockIdx.x < 5) { deg = deg_pm; bsum = bsum_pm; rp = rp_pm; n = NMHC; nb = 5; bi = blockIdx.x; mode = 0; }
    else if (blockIdx.x < 103) { deg = deg_mt; bsum = bsum_mt; rp = rp_mt; n = NTCR; nb = 98; bi = blockIdx.x - 5; mode = 0; }
    else { deg = mark; bsum = bsum_mk; rp = nullptr; n = NTCR; nb = 98; bi = blockIdx.x - 103; mode = 1; }
    tsum[tid] = (tid < bi) ? bsum[tid] : 0;
    __syncthreads();
    for (int off = 128; off > 0; off >>= 1) {
        if (tid < off) tsum[tid] += tsum[tid + off];
        __syncthreads();
    }
    const int base = tsum[0];
    __syncthreads();
    const int i0 = bi * 1024 + tid * 4;
    int4 v = make_int4(0, 0, 0, 0);
    if (i0 + 3 < n) v = *(const int4*)(deg + i0);
    else if (i0 < n) {
        int t[4] = {0, 0, 0, 0};
        for (int j = 0; j < 4 && i0 + j < n; j++) t[j] = deg[i0 + j];
        v = make_int4(t[0], t[1], t[2], t[3]);
    }
    tsum[tid] = v.x + v.y + v.z + v.w;
    __syncthreads();
    for (int off = 1; off < 256; off <<= 1) {
        int t = (tid >= off) ? tsum[tid - off] : 0;
        __syncthreads();
        tsum[tid] += t;
        __syncthreads();
    }
    int ex = ((tid > 0) ? tsum[tid - 1] : 0) + base;
    if (mode == 0) {
        if (i0 + 3 < n) {
            int r1 = ex + v.x, r2 = r1 + v.y, r3 = r2 + v.z;
            *(int4*)(rp + i0) = make_int4(ex, r1, r2, r3);
        } else if (i0 < n) {
            int r = ex;
            int vv[4] = {v.x, v.y, v.z, v.w};
            for (int j = 0; j < 4 && i0 + j < n; j++) { rp[i0 + j] = r; r += vv[j]; }
        }
        if (bi == nb - 1 && tid == 255) rp[n] = base + tsum[255];
    } else {
        int p = ex;
        int vv[4] = {v.x, v.y, v.z, v.w};
#pragma unroll
        for (int j = 0; j < 4; j++) {
            if (i0 + j < n && vv[j]) { list[p] = i0 + j; inv[i0 + j] = p; p++; }
        }
        if (bi == nb - 1 && tid == 255) nrows[0] = base + tsum[255];
    }
}

// ---------------- merged CSR fill ----------------
__global__ void fill2_kernel(const int* __restrict__ src_pm, const int* __restrict__ dst_pm,
                             const int* __restrict__ src_mt, const int* __restrict__ dst_mt,
                             const int* __restrict__ rp_pm, int* __restrict__ cur_pm, int* __restrict__ csr_pm,
                             const int* __restrict__ rp_mt, int* __restrict__ cur_mt, int* __restrict__ csr_mt) {
    int t = blockIdx.x * blockDim.x + threadIdx.x;
    if (t < EPM) {
        int d = dst_pm[t];
        int pos = atomicAdd(&cur_pm[d], 1);
        csr_pm[rp_pm[d] + pos] = src_pm[t];
    } else if (t < EPM + EMT) {
        int t2 = t - EPM;
        int d = dst_mt[t2];
        int pos = atomicAdd(&cur_mt[d], 1);
        csr_mt[rp_mt[d] + pos] = src_mt[t2];
    }
}

// ---------------- merged: pm gather (shfl-parallel) + pt remap ----------------
__global__ __launch_bounds__(256) void gph_kernel(
    const int* __restrict__ rp, const int* __restrict__ csr_src,
    const float* __restrict__ X, ushort* __restrict__ A1, ushort* __restrict__ A2,
    const int* __restrict__ pack_tcr, const int* __restrict__ inv, int* __restrict__ pt_c) {
    const int tid = threadIdx.x;
    const int b = blockIdx.x;
    if (b < 625) {
        const int r = b * 8 + (tid >> 5);
        const int lane = tid & 31;
        if (r >= NMHC) return;
        const int e0 = rp[r], e1 = rp[r + 1];
        float4 s = make_float4(0.f, 0.f, 0.f, 0.f);
        for (int eb = e0; eb < e1; eb += 32) {
            int dc = min(32, e1 - eb);
            int sidx_l = (lane < dc) ? csr_src[eb + lane] : 0;
            for (int e = 0; e < dc; e++) {
                int sidx = __shfl(sidx_l, e, 32);
                float4 v = ((const float4*)(X + (long)sidx * 128))[lane];
                s.x += v.x; s.y += v.y; s.z += v.z; s.w += v.w;
            }
        }
        float sc = 1.f / fmaxf((float)(e1 - e0), 1.f);
        ushort4 o = make_ushort4(f2bf(s.x * sc), f2bf(s.y * sc), f2bf(s.z * sc), f2bf(s.w * sc));
        *(ushort4*)(A1 + (size_t)r * 256 + lane * 4) = o;
        *(ushort4*)(A2 + (size_t)r * 384 + lane * 4) = o;
    } else {
        int i = (b - 625) * 256 + tid;
        if (i < BB) pt_c[i] = inv[pack_tcr[i]];
    }
}

// ---------------- mhc fused GEMM launch + Hp tiles ----------------
template <int K>
__global__ __launch_bounds__(256, 2) void fusedhp_kernel(
    int M, const ushort* __restrict__ A, const ushort* __restrict__ W,
    const float* __restrict__ bias,
    ushort* __restrict__ out0, int s0, ushort* __restrict__ out1,
    int hpBy, const float* __restrict__ emb_pep, const ushort* __restrict__ Wcomp,
    const float* __restrict__ bp, ushort* __restrict__ Hp) {
    __shared__ ushort Als[128 * RS];
    __shared__ ushort Wls[128 * RS];
    const int tid = threadIdx.x;
    const int b = blockIdx.x;
    if (b < 160)
        fused_tile<K, 2>(Als, Wls, tid, b % 40, b / 40, M, A, W, bias, out0, s0, out1);
    else
        out_tile<128, true, true>(Als, Wls, tid, b - 160, hpBy, NPEP, emb_pep, Wcomp, bp, Hp);
}

// ---------------- fused TCR chain (3-buffer LDS, single dual-Z walk) + Hm GEMM ----------------
__global__ __launch_bounds__(256, 3) void tcrhm_kernel(
    const int* __restrict__ nrowsp, const int* __restrict__ list,
    const int* __restrict__ rp, const int* __restrict__ csr_src,
    const ushort* __restrict__ Z1, const ushort* __restrict__ Z2,
    const float* __restrict__ emb_tcr,
    const ushort* __restrict__ Wr1, const ushort* __restrict__ Wr2,
    const ushort* __restrict__ W1c,
    const float* __restrict__ bl1, const float* __restrict__ bl2,
    ushort* __restrict__ Ht_c,
    const ushort* __restrict__ mhc2, const ushort* __restrict__ W1b,
    ushort* __restrict__ Hm) {
    union SM {
        struct { ushort B[32 * RS2]; ushort A1[32 * RS2]; ushort A2[32 * RS2]; } t;  // 50688 B
        struct { ushort Als[128 * RS]; ushort Wls[128 * RS]; } g;
    };
    __shared__ SM sm;
    const int tid = threadIdx.x;

    if (blockIdx.x >= 1563) {
        int v = blockIdx.x - 1563;             // 0..79
        out_tile<256, false, false>(sm.g.Als, sm.g.Wls, tid, v % 40, v / 40, NMHC,
                                    mhc2, W1b, nullptr, Hm);
        return;
    }

    const int M = nrowsp[0];
    const int m0 = blockIdx.x * 32;
    if (m0 >= M) return;
    const int lane = tid & 63, w = tid >> 6;   // wave w: cols w*64..w*64+63
    const int m16 = lane & 15, q = lane >> 4;

    // ---- stage 0: emb_tcr rows f32->bf16 -> B (RS1) ----
#pragma unroll
    for (int r = 0; r < 4; r++) {
        int chunk = tid + r * 256;             // 1024 chunks: 32 rows x 32 float4
        int row = chunk >> 5, c4 = (chunk & 31) * 4;
        int grow = list[min(m0 + row, M - 1)];
        float4 v = *(const float4*)(emb_tcr + (size_t)grow * 128 + c4);
        *(ushort4*)(&sm.t.B[row * RS1 + c4]) = f4bf(v);
    }

    // ---- SINGLE dual-Z neighbor-mean walk -> A1, A2 (pre-scaled); sidx broadcast via shfl ----
    {
        const int g = tid >> 5, gl = tid & 31;
        for (int rr = g; rr < 32; rr += 8) {
            int cr = min(m0 + rr, M - 1);
            int orig = list[cr];
            int e0 = rp[orig], e1 = rp[orig + 1];
            int deg = e1 - e0;
            float s1[8] = {}, s2[8] = {};
            for (int eb = e0; eb < e1; eb += 32) {
                int dc = min(32, e1 - eb);
                int sidx_l = (gl < dc) ? csr_src[eb + gl] : 0;
                for (int e = 0; e < dc; e++) {
                    int sidx = __shfl(sidx_l, e, 32);
                    uint4 u1 = *(const uint4*)(Z1 + (size_t)sidx * 256 + gl * 8);
                    uint4 u2 = *(const uint4*)(Z2 + (size_t)sidx * 256 + gl * 8);
                    float x, y;
                    bf2x2(u1.x, x, y); s1[0] += x; s1[1] += y;
                    bf2x2(u1.y, x, y); s1[2] += x; s1[3] += y;
                    bf2x2(u1.z, x, y); s1[4] += x; s1[5] += y;
                    bf2x2(u1.w, x, y); s1[6] += x; s1[7] += y;
                    bf2x2(u2.x, x, y); s2[0] += x; s2[1] += y;
                    bf2x2(u2.y, x, y); s2[2] += x; s2[3] += y;
                    bf2x2(u2.z, x, y); s2[4] += x; s2[5] += y;
                    bf2x2(u2.w, x, y); s2[6] += x; s2[7] += y;
                }
            }
            float es = 1.f / fmaxf((float)deg, 1.f);
            uint4 w1, w2;
            w1.x = (unsigned)f2bf(s1[0] * es) | ((unsigned)f2bf(s1[1] * es) << 16);
            w1.y = (unsigned)f2bf(s1[2] * es) | ((unsigned)f2bf(s1[3] * es) << 16);
            w1.z = (unsigned)f2bf(s1[4] * es) | ((unsigned)f2bf(s1[5] * es) << 16);
            w1.w = (unsigned)f2bf(s1[6] * es) | ((unsigned)f2bf(s1[7] * es) << 16);
            w2.x = (unsigned)f2bf(s2[0] * es) | ((unsigned)f2bf(s2[1] * es) << 16);
            w2.y = (unsigned)f2bf(s2[2] * es) | ((unsigned)f2bf(s2[3] * es) << 16);
            w2.z = (unsigned)f2bf(s2[4] * es) | ((unsigned)f2bf(s2[5] * es) << 16);
            w2.w = (unsigned)f2bf(s2[6] * es) | ((unsigned)f2bf(s2[7] * es) << 16);
            *(uint4*)(&sm.t.A1[rr * RS2 + gl * 8]) = w1;
            *(uint4*)(&sm.t.A2[rr * RS2 + gl * 8]) = w2;
        }
    }
    __syncthreads();

    // ---- stage 1a: T1 = relu(etc @ Wr1^T + bl1 + A1) ----
    {
        f32x4 acc[2][4] = {};
        for (int k0 = 0; k0 < 128; k0 += 32) {
            bf16x8 af[2], bf[4];
#pragma unroll
            for (int t = 0; t < 2; t++)
                af[t] = *(const bf16x8*)(&sm.t.B[(t * 16 + m16) * RS1 + k0 + q * 8]);
#pragma unroll
            for (int t = 0; t < 4; t++)
                bf[t] = *(const bf16x8*)(Wr1 + (size_t)(w * 64 + t * 16 + m16) * 128 + k0 + q * 8);
#pragma unroll
            for (int mt = 0; mt < 2; mt++)
#pragma unroll
                for (int nt = 0; nt < 4; nt++)
                    acc[mt][nt] = __builtin_amdgcn_mfma_f32_16x16x32_bf16(af[mt], bf[nt], acc[mt][nt], 0, 0, 0);
        }
        __syncthreads();                       // B reads done before rewrite
#pragma unroll
        for (int mt = 0; mt < 2; mt++)
#pragma unroll
            for (int i = 0; i < 4; i++) {
                int lr = mt * 16 + q * 4 + i;
#pragma unroll
                for (int nt = 0; nt < 4; nt++) {
                    int col = w * 64 + nt * 16 + m16;
                    float v = acc[mt][nt][i] + bl1[col] + bf2f(sm.t.A1[lr * RS2 + col]);
                    sm.t.B[lr * RS2 + col] = f2bf(fmaxf(v, 0.f));
                }
            }
    }
    __syncthreads();

    // ---- stage 1b: T = relu(T1 @ Wr2^T + bl2 + A2) ----
    {
        f32x4 acc[2][4] = {};
        for (int k0 = 0; k0 < 256; k0 += 32) {
            bf16x8 af[2], bf[4];
#pragma unroll
            for (int t = 0; t < 2; t++)
                af[t] = *(const bf16x8*)(&sm.t.B[(t * 16 + m16) * RS2 + k0 + q * 8]);
#pragma unroll
            for (int t = 0; t < 4; t++)
                bf[t] = *(const bf16x8*)(Wr2 + (size_t)(w * 64 + t * 16 + m16) * 256 + k0 + q * 8);
#pragma unroll
            for (int mt = 0; mt < 2; mt++)
#pragma unroll
                for (int nt = 0; nt < 4; nt++)
                    acc[mt][nt] = __builtin_amdgcn_mfma_f32_16x16x32_bf16(af[mt], bf[nt], acc[mt][nt], 0, 0, 0);
        }
        __syncthreads();
#pragma unroll
        for (int mt = 0; mt < 2; mt++)
#pragma unroll
            for (int i = 0; i < 4; i++) {
                int lr = mt * 16 + q * 4 + i;
#pragma unroll
                for (int nt = 0; nt < 4; nt++) {
                    int col = w * 64 + nt * 16 + m16;
                    float v = acc[mt][nt][i] + bl2[col] + bf2f(sm.t.A2[lr * RS2 + col]);
                    sm.t.B[lr * RS2 + col] = f2bf(fmaxf(v, 0.f));
                }
            }
    }
    __syncthreads();

    // ---- stage 2: Ht_tile = T @ W1c^T -> B ----
    {
        f32x4 acc[2][4] = {};
        for (int k0 = 0; k0 < 256; k0 += 32) {
            bf16x8 af[2], bf[4];
#pragma unroll
            for (int t = 0; t < 2; t++)
                af[t] = *(const bf16x8*)(&sm.t.B[(t * 16 + m16) * RS2 + k0 + q * 8]);
#pragma unroll
            for (int t = 0; t < 4; t++)
                bf[t] = *(const bf16x8*)(W1c + (size_t)(w * 64 + t * 16 + m16) * 256 + k0 + q * 8);
#pragma unroll
            for (int mt = 0; mt < 2; mt++)
#pragma unroll
                for (int nt = 0; nt < 4; nt++)
                    acc[mt][nt] = __builtin_amdgcn_mfma_f32_16x16x32_bf16(af[mt], bf[nt], acc[mt][nt], 0, 0, 0);
        }
        __syncthreads();
#pragma unroll
        for (int mt = 0; mt < 2; mt++)
#pragma unroll
            for (int i = 0; i < 4; i++) {
                int lr = mt * 16 + q * 4 + i;
#pragma unroll
                for (int nt = 0; nt < 4; nt++) {
                    int col = w * 64 + nt * 16 + m16;
                    sm.t.B[lr * RS2 + col] = f2bf(acc[mt][nt][i]);
                }
            }
    }
    __syncthreads();

    // coalesced COMPACT writeback
#pragma unroll
    for (int r = 0; r < 4; r++) {
        int chunk = tid + r * 256;
        int row = chunk >> 5, c8 = (chunk & 31) * 8;
        if (m0 + row < M)
            *(uint4*)(Ht_c + (size_t)(m0 + row) * 256 + c8) = *(const uint4*)(&sm.t.B[row * RS2 + c8]);
    }
}

// ---------------- combine ----------------
__global__ __launch_bounds__(256) void combine_kernel(
    const ushort* __restrict__ Hp, const ushort* __restrict__ Hm, const ushort* __restrict__ Ht,
    const int* __restrict__ pp, const int* __restrict__ pm, const int* __restrict__ pt_c,
    const float* __restrict__ b1, const float* __restrict__ W2, const float* __restrict__ b2,
    float* __restrict__ out) {
    const int tid = threadIdx.x;
    const int lane = tid & 63, w = tid >> 6;
    const int c = lane * 4;
    const float4 b1v = *(const float4*)(b1 + c);
    const float4 w2v = *(const float4*)(W2 + c);
    const float b2v = b2[0];
    const int base = blockIdx.x * 32 + w * 8;
#pragma unroll
    for (int t = 0; t < 8; t++) {
        int i = base + t;
        if (i >= BB) return;
        int ra = pp[i], rb = pm[i], rc = pt_c[i];
        ushort4 ua = *(const ushort4*)(Hp + (size_t)ra * 256 + c);
        ushort4 ub = *(const ushort4*)(Hm + (size_t)rb * 256 + c);
        ushort4 uc = *(const ushort4*)(Ht + (size_t)rc * 256 + c);
        float h0 = fmaxf(bf2f(ua.x) + bf2f(ub.x) + bf2f(uc.x) + b1v.x, 0.f);
        float h1 = fmaxf(bf2f(ua.y) + bf2f(ub.y) + bf2f(uc.y) + b1v.y, 0.f);
        float h2 = fmaxf(bf2f(ua.z) + bf2f(ub.z) + bf2f(uc.z) + b1v.z, 0.f);
        float h3 = fmaxf(bf2f(ua.w) + bf2f(ub.w) + bf2f(uc.w) + b1v.w, 0.f);
        float p = h0 * w2v.x + h1 * w2v.y + h2 * w2v.z + h3 * w2v.w;
#pragma unroll
        for (int off = 32; off > 0; off >>= 1) p += __shfl_down(p, off);
        if (lane == 0) out[i] = p + b2v;
    }
}

// ---------------- launch ----------------
extern "C" void kernel_launch(void* const* d_in, const int* in_sizes, int n_in,
                              void* d_out, int out_size, void* d_ws, size_t ws_size,
                              hipStream_t stream) {
    const float* emb_pep = (const float*)d_in[0];
    const float* emb_mhc = (const float*)d_in[1];
    const float* emb_tcr = (const float*)d_in[2];
    const int* src_pm = (const int*)d_in[3];
    const int* dst_pm = (const int*)d_in[4];
    const int* src_mt = (const int*)d_in[5];
    const int* dst_mt = (const int*)d_in[6];
    const int* pack_pep = (const int*)d_in[7];
    const int* pack_mhc = (const int*)d_in[8];
    const int* pack_tcr = (const int*)d_in[9];
    const float* l1_pm_Wl = (const float*)d_in[10];
    const float* l1_pm_bl = (const float*)d_in[11];
    const float* l1_pm_Wr = (const float*)d_in[12];
    const float* l1_mt_Wl = (const float*)d_in[13];
    const float* l1_mt_bl = (const float*)d_in[14];
    const float* l1_mt_Wr = (const float*)d_in[15];
    const float* l2_pm_Wl = (const float*)d_in[16];
    const float* l2_pm_bl = (const float*)d_in[17];
    const float* l2_pm_Wr = (const float*)d_in[18];
    const float* l2_mt_Wl = (const float*)d_in[19];
    const float* l2_mt_bl = (const float*)d_in[20];
    const float* l2_mt_Wr = (const float*)d_in[21];
    const float* proj_W = (const float*)d_in[22];
    const float* proj_b = (const float*)d_in[23];
    const float* head_W1 = (const float*)d_in[24];
    const float* head_b1 = (const float*)d_in[25];
    const float* head_W2 = (const float*)d_in[26];
    const float* head_b2 = (const float*)d_in[27];
    float* out = (float*)d_out;

    // ---------------- workspace layout ----------------
    int* ib = (int*)d_ws;
    int* deg_pm = ib;                 // 5000
    int* cur_pm = ib + 5000;          // 5000
    int* deg_mt = ib + 10000;         // 100000
    int* cur_mt = ib + 110000;        // 100000
    int* mark   = ib + 210000;        // 100000  [zero region: first 310000 ints, via memset]
    int* rp_pm  = ib + 310000;        // 5001 (pad 5008)
    int* rp_mt  = ib + 315008;        // 100001 (pad 100008)
    int* csr_pm = ib + 415016;        // 200000
    int* csr_mt = ib + 615016;        // 400000
    int* bsum_pm = ib + 1015016;      // 160
    int* bsum_mt = ib + 1015176;      // 160
    int* bsum_mk = ib + 1015336;      // 160
    int* nrows   = ib + 1015496;      // 8
    int* list    = ib + 1015504;      // 50048 -> 1065552
    int* inv     = ib + 1065552;      // 100000 -> 1165552
    int* pt_c    = ib + 1165552;      // 50048 -> 1215600

    float* f = (float*)(ib + 1215600);
    float* bp = f;                    // 256

    ushort* u = (ushort*)(f + 256);
    ushort* Wcat1_b = u;              // 131072
    ushort* Wcat2_b = u + 131072;     // 196608
    ushort* W1b_b   = u + 327680;     // 65536
    ushort* W1c_b   = u + 393216;     // 65536
    ushort* Wcomp_b = u + 458752;     // 32768
    ushort* Wr1_b   = u + 491520;     // 32768
    ushort* Wr2_b   = u + 524288;     // 65536
    ushort* Acat1   = u + 589824;     // 1280000
    ushort* Acat2   = u + 1869824;    // 1920000
    ushort* Zb1     = u + 3789824;    // 1280000
    ushort* Zb2     = u + 5069824;    // 1280000
    ushort* mhc2_b  = u + 6349824;    // 1280000
    ushort* Hp_b    = u + 7629824;    // 5120000
    ushort* Hm_b    = u + 12749824;   // 1280000
    ushort* Ht_c    = u + 14029824;   // 12800000 (50000x256 compact)

    // 0. zero deg/cur/mark (stream-ordered DMA)
    hipMemsetAsync(ib, 0, 310000 * sizeof(int), stream);

    // 1. merged prep + histogram
    preph_kernel<<<4925, 256, 0, stream>>>(
        dst_pm, dst_mt, pack_tcr, deg_pm, deg_mt, mark,
        (const float4*)l1_mt_Wr, (ushort4*)Wr1_b,
        (const float4*)l2_mt_Wr, (ushort4*)Wr2_b,
        head_W1, (ushort4*)W1b_b, (ushort4*)W1c_b,
        l1_pm_Wl, l1_pm_Wr, l1_mt_Wl, Wcat1_b,
        l2_pm_Wl, l2_pm_Wr, l2_mt_Wl, Wcat2_b,
        (const float4*)emb_mhc, Acat1,
        proj_W, proj_b, Wcomp_b, bp);

    // 2-4. CSR build + compaction
    blocksum2_kernel<<<201, 256, 0, stream>>>(deg_pm, deg_mt, mark, bsum_pm, bsum_mt, bsum_mk);
    emit2_kernel<<<201, 256, 0, stream>>>(deg_pm, deg_mt, mark, bsum_pm, bsum_mt, bsum_mk,
                                          rp_pm, rp_mt, list, inv, nrows);
    fill2_kernel<<<(EPM + EMT + 255) / 256, 256, 0, stream>>>(
        src_pm, dst_pm, src_mt, dst_mt, rp_pm, cur_pm, csr_pm, rp_mt, cur_mt, csr_mt);

    // 5. pm gather + pt remap
    gph_kernel<<<821, 256, 0, stream>>>(
        rp_pm, csr_pm, emb_pep, Acat1, Acat2, pack_tcr, inv, pt_c);

    // 6-7. mhc layers + Hp halves
    fusedhp_kernel<256><<<317, 256, 0, stream>>>(
        NMHC, Acat1, Wcat1_b, l1_pm_bl, Acat2 + 128, 384, Zb1,
        0, emb_pep, Wcomp_b, bp, Hp_b);
    fusedhp_kernel<384><<<317, 256, 0, stream>>>(
        NMHC, Acat2, Wcat2_b, l2_pm_bl, mhc2_b, 256, Zb2,
        1, emb_pep, Wcomp_b, bp, Hp_b);

    // 8. fused tcr chain (compact Ht) + Hm tiles
    tcrhm_kernel<<<1563 + 80, 256, 0, stream>>>(
        nrows, list, rp_mt, csr_mt, Zb1, Zb2, emb_tcr,
        Wr1_b, Wr2_b, W1c_b, l1_mt_bl, l2_mt_bl, Ht_c,
        mhc2_b, W1b_b, Hm_b);

    // 9. combine
    combine_kernel<<<(BB + 31) / 32, 256, 0, stream>>>(
        Hp_b, Hm_b, Ht_c, pack_pep, pack_mhc, pt_c,
        head_b1, head_W2, head_b2, out);
}